// Round 10
// baseline (382.959 us; speedup 1.0000x reference)
//
#include <hip/hip_runtime.h>
#include <hip/hip_bf16.h>
#include <stdint.h>

// Problem constants
#define B_  8
#define S_  2048
#define D_  768
#define H_  12
#define HD_ 64
#define BH_ (B_*H_)   // 96
#define M_  (B_*S_)   // 16384

typedef __bf16 bf16;
typedef __bf16 bf16x8 __attribute__((ext_vector_type(8)));
typedef __bf16 bf16x4 __attribute__((ext_vector_type(4)));
typedef short  short4v __attribute__((ext_vector_type(4)));
typedef float  f32x4  __attribute__((ext_vector_type(4)));

// Q pre-scale folds log2(e) so softmax uses native exp2 (v_exp_f32 IS exp2):
// 1/(8+1e-6) * log2(e); exp2(S*log2e) == exp(S).
#define QSCALE2 0.18033685756901243f

#if __has_builtin(__builtin_amdgcn_exp2f)
#define EXP2(x) __builtin_amdgcn_exp2f(x)
#else
#define EXP2(x) exp2f(x)
#endif

// LDS-only barrier: orders ds ops across the workgroup WITHOUT draining vmcnt.
#define LDS_BARRIER() asm volatile("s_waitcnt lgkmcnt(0)\n\ts_barrier" ::: "memory")

// global -> LDS direct copy, 16 B per lane (dest = uniform base + lane*16).
#define GLD16(gptr, lptr) __builtin_amdgcn_global_load_lds( \
    (const __attribute__((address_space(1))) uint32_t*)(gptr), \
    (__attribute__((address_space(3))) uint32_t*)(lptr), 16, 0, 0)

// 16x16x16 bf16 MFMA: A-layout == C/D-layout-transposed, the key identity.
#if __has_builtin(__builtin_amdgcn_mfma_f32_16x16x16bf16_1k)
static __device__ inline f32x4 mfma16(bf16x4 a, bf16x4 b, f32x4 c) {
  return __builtin_amdgcn_mfma_f32_16x16x16bf16_1k(
      __builtin_bit_cast(short4v, a), __builtin_bit_cast(short4v, b), c, 0, 0, 0);
}
#else
// fallback: zero-pad halves into the known-good 16x16x32 (same result)
static __device__ inline f32x4 mfma16(bf16x4 a, bf16x4 b, f32x4 c) {
  bf16 z = (bf16)0.f;
  bf16x8 a8 = {a[0], a[1], a[2], a[3], z, z, z, z};
  bf16x8 b8 = {b[0], b[1], b[2], b[3], z, z, z, z};
  return __builtin_amdgcn_mfma_f32_16x16x32_bf16(a8, b8, c, 0, 0, 0);
}
#endif

// ---------------------------------------------------------------------------
// fp32 -> bf16 elementwise convert, 8 elems/thread
// ---------------------------------------------------------------------------
__global__ __launch_bounds__(256) void f2b(const float* __restrict__ src,
                                           bf16* __restrict__ dst, int n) {
  int i = (blockIdx.x * 256 + threadIdx.x) * 8;
  if (i >= n) return;
  float4 a = *(const float4*)(src + i);
  float4 b = *(const float4*)(src + i + 4);
  bf16 o[8] = {(bf16)a.x, (bf16)a.y, (bf16)a.z, (bf16)a.w,
               (bf16)b.x, (bf16)b.y, (bf16)b.z, (bf16)b.w};
  *(uint4*)(dst + i) = *(const uint4*)o;
}

// ---------------------------------------------------------------------------
// 64x64-tile transpose + fp32->bf16: src f32 [mat][R][C] -> dst bf16 [mat][C][R]
// (still used for Wp)
// ---------------------------------------------------------------------------
__global__ __launch_bounds__(256) void transpose64_f2b(const float* __restrict__ src,
                                                       bf16* __restrict__ dst,
                                                       int R, int C) {
  __shared__ bf16 t[64][72];
  int mat = blockIdx.z;
  const float* s = src + (size_t)mat * R * C;
  bf16* d = dst + (size_t)mat * C * R;
  int r0 = blockIdx.x * 64, c0 = blockIdx.y * 64;
  int tid = threadIdx.x;
  #pragma unroll
  for (int it = 0; it < 4; ++it) {
    int i = (tid >> 4) + it * 16;
    int j = (tid & 15) * 4;
    float4 v = *(const float4*)(s + (size_t)(r0 + i) * C + c0 + j);
    t[j + 0][i] = (bf16)v.x; t[j + 1][i] = (bf16)v.y;
    t[j + 2][i] = (bf16)v.z; t[j + 3][i] = (bf16)v.w;
  }
  __syncthreads();
  #pragma unroll
  for (int it = 0; it < 4; ++it) {
    int i = (tid >> 4) + it * 16;
    int j = (tid & 15) * 4;
    bf16* p = d + (size_t)(c0 + i) * R + r0 + j;
    p[0] = t[i][j]; p[1] = t[i][j + 1]; p[2] = t[i][j + 2]; p[3] = t[i][j + 3];
  }
}

// ---------------------------------------------------------------------------
// Fused prep: transpose Wq|Wk|Wv (36 head-tiles of [768][64] -> [64][768])
// into Wt[2304][768], plus bias packing (z==36). Replaces 4 launches with 1.
// ---------------------------------------------------------------------------
__global__ __launch_bounds__(256) void prep_w(
    const float* __restrict__ Wq, const float* __restrict__ Wk,
    const float* __restrict__ Wv, const float* __restrict__ bq,
    const float* __restrict__ bk, const float* __restrict__ bv,
    bf16* __restrict__ Wt, float* __restrict__ ball)
{
  int z = blockIdx.z;
  int tid = threadIdx.x;
  if (z == 36) {   // bias pack: 12 blocks x 256 threads >= 2304
    int i = blockIdx.x * 256 + tid;
    if (i < 2304) {
      float v = (i < 768) ? bq[i] : (i < 1536 ? bk[i - 768] : bv[i - 1536]);
      ball[i] = v;
    }
    return;
  }
  __shared__ bf16 t[64][72];
  int w = z / 12, h = z % 12;
  const float* s = (w == 0 ? Wq : (w == 1 ? Wk : Wv)) + (size_t)h * 768 * 64;
  bf16* d = Wt + (size_t)z * 64 * 768;          // [64][768] head-tile
  int r0 = blockIdx.x * 64;                      // over R=768
  #pragma unroll
  for (int it = 0; it < 4; ++it) {
    int i = (tid >> 4) + it * 16;
    int j = (tid & 15) * 4;
    float4 v = *(const float4*)(s + (size_t)(r0 + i) * 64 + j);
    t[j + 0][i] = (bf16)v.x; t[j + 1][i] = (bf16)v.y;
    t[j + 2][i] = (bf16)v.z; t[j + 3][i] = (bf16)v.w;
  }
  __syncthreads();
  #pragma unroll
  for (int it = 0; it < 4; ++it) {
    int i = (tid >> 4) + it * 16;
    int j = (tid & 15) * 4;
    bf16* p = d + (size_t)i * 768 + r0 + j;
    p[0] = t[i][j]; p[1] = t[i][j + 1]; p[2] = t[i][j + 2]; p[3] = t[i][j + 3];
  }
}

// ---------------------------------------------------------------------------
// GEMM: C[M,N] = A[M,K](bf16) * Bt[N,K]^T(bf16) + bias[N](fp32)
// 128x128 tile, BK=32, 256 threads (4 waves, 2x2), mfma_f32_16x16x32_bf16.
// ASYNC ping-pong staging (r8 flash recipe). __launch_bounds__(256,4):
// 4 blocks/CU (LDS 32KB each; live regs ~64 acc AGPR + ~50 arch < 128 cap)
// -> 4 waves/SIMD of TLP to cover the distance-1 prefetch's latency residue
// (16 MFMA/iter ~= 130-250 cyc < ~200-500 cyc L2 latency; same diagnosis
// that took flash 249->154 us).
// Rule-#21 swizzle: linear LDS dest, inverse-XOR'd global source, same XOR
// on ds_read (slot ^= row&3 within 64B rows).
// MODE 0: fp32 row-major C. MODE 1: scatter Q (pre-scaled)/K to [B,H,S,64]
//         and V to V^T layout [bh][64][S] (bf16), all with bias.
// ---------------------------------------------------------------------------
template <int MODE>
__global__ __launch_bounds__(256, 4) void gemm_bt(
    const bf16* __restrict__ A, const bf16* __restrict__ Bt,
    const float* __restrict__ bias, float* __restrict__ C,
    bf16* __restrict__ Qo, bf16* __restrict__ Ko, bf16* __restrict__ Vo,
    int Mdim, int Ndim, int Kdim)
{
  // buf b at b*8192 elems: [As 4096 | Bs 4096]; 32 KB total
  __shared__ bf16 smem[16384];
  int tid = threadIdx.x;
  int wave = tid >> 6, lane = tid & 63;
  int wm = wave & 1, wn = wave >> 1;
  int m0 = blockIdx.x * 128, n0 = blockIdx.y * 128;
  int lm = lane & 15, lq = lane >> 4;

  int c0_ = wave * 2;
  int r_in = lane >> 2;                     // 0..15
  int ps   = lane & 3;                      // physical 16B slot in 64B row
  int rowA0 = c0_ * 16 + r_in;              // chunk 2w row
  int rowA1 = rowA0 + 16;                   // chunk 2w+1 row
  int ls0 = ps ^ (rowA0 & 3);               // logical slot (inverse swizzle)
  int ls1 = ps ^ (rowA1 & 3);

  f32x4 zero = {0.f, 0.f, 0.f, 0.f};
  f32x4 acc[4][4];
  #pragma unroll
  for (int i = 0; i < 4; ++i)
    #pragma unroll
    for (int j = 0; j < 4; ++j) acc[i][j] = zero;

  int NK = Kdim >> 5;

  // prologue: stage k=0 into buf0, full drain
  GLD16(A  + (size_t)(m0 + rowA0) * Kdim + ls0 * 8, &smem[c0_ * 512]);
  GLD16(A  + (size_t)(m0 + rowA1) * Kdim + ls1 * 8, &smem[c0_ * 512 + 512]);
  GLD16(Bt + (size_t)(n0 + rowA0) * Kdim + ls0 * 8, &smem[4096 + c0_ * 512]);
  GLD16(Bt + (size_t)(n0 + rowA1) * Kdim + ls1 * 8, &smem[4096 + c0_ * 512 + 512]);
  __syncthreads();   // vmcnt(0)+lgkm(0)+barrier: tile 0 resident

  for (int kk = 0; kk < NK; ++kk) {
    int cb = (kk & 1) << 13;   // current buf base (elems)
    int nb = 8192 - cb;        // next buf base

    if (kk + 1 < NK) {         // issue tile kk+1 staging EARLY
      int k0 = (kk + 1) * 32;
      GLD16(A  + (size_t)(m0 + rowA0) * Kdim + k0 + ls0 * 8, &smem[nb + c0_ * 512]);
      GLD16(A  + (size_t)(m0 + rowA1) * Kdim + k0 + ls1 * 8, &smem[nb + c0_ * 512 + 512]);
      GLD16(Bt + (size_t)(n0 + rowA0) * Kdim + k0 + ls0 * 8, &smem[nb + 4096 + c0_ * 512]);
      GLD16(Bt + (size_t)(n0 + rowA1) * Kdim + k0 + ls1 * 8, &smem[nb + 4096 + c0_ * 512 + 512]);
    }

    bf16x8 af[4], bfr[4];
    #pragma unroll
    for (int i = 0; i < 4; ++i) {
      int ra = wm * 64 + i * 16 + lm;
      af[i] = *(const bf16x8*)(&smem[cb + ra * 32 + ((lq ^ (ra & 3)) * 8)]);
    }
    #pragma unroll
    for (int j = 0; j < 4; ++j) {
      int rb = wn * 64 + j * 16 + lm;
      bfr[j] = *(const bf16x8*)(&smem[cb + 4096 + rb * 32 + ((lq ^ (rb & 3)) * 8)]);
    }
    __builtin_amdgcn_s_setprio(1);
    #pragma unroll
    for (int i = 0; i < 4; ++i)
      #pragma unroll
      for (int j = 0; j < 4; ++j)
        acc[i][j] = __builtin_amdgcn_mfma_f32_16x16x32_bf16(af[i], bfr[j], acc[i][j], 0, 0, 0);
    __builtin_amdgcn_s_setprio(0);

    // staging loads landed (hidden under the MFMAs), then LDS-ordered barrier
    asm volatile("s_waitcnt vmcnt(0)" ::: "memory");
    LDS_BARRIER();
  }

  int mbase = m0 + wm * 64, nbase = n0 + wn * 64;
  #pragma unroll
  for (int j = 0; j < 4; ++j) {
    int n = nbase + j * 16 + lm;
    float bv_ = bias[n];
    if (MODE == 0) {
      #pragma unroll
      for (int i = 0; i < 4; ++i)
        #pragma unroll
        for (int r = 0; r < 4; ++r) {
          int m = mbase + i * 16 + lq * 4 + r;
          C[(size_t)m * Ndim + n] = acc[i][j][r] + bv_;
        }
    } else {
      int which = n / 768;             // uniform per block (768 = 6*128)
      int rem = n - which * 768;
      int h = rem >> 6, e = rem & 63;
      float scl = (which == 0) ? QSCALE2 : 1.0f;
      if (which == 2) {
        #pragma unroll
        for (int i = 0; i < 4; ++i)
          #pragma unroll
          for (int r = 0; r < 4; ++r) {
            int m = mbase + i * 16 + lq * 4 + r;
            int b = m >> 11, s = m & 2047;
            Vo[((size_t)(b * H_ + h) * 64 + e) * S_ + s] = (bf16)(acc[i][j][r] + bv_);
          }
      } else {
        bf16* dst = (which == 0) ? Qo : Ko;
        #pragma unroll
        for (int i = 0; i < 4; ++i)
          #pragma unroll
          for (int r = 0; r < 4; ++r) {
            int m = mbase + i * 16 + lq * 4 + r;
            int b = m >> 11, s = m & 2047;
            dst[((size_t)(b * H_ + h) * S_ + s) * 64 + e] = (bf16)((acc[i][j][r] + bv_) * scl);
          }
      }
    }
  }
}

// ---------------------------------------------------------------------------
// Flash attention v2 (r8 winner, UNTOUCHED): global_load_lds K/V staging,
// ping-pong LDS, issue-early/drain-late, 1 barrier/iter, rule-#21 swizzle,
// setprio around MFMA clusters. 153.7 us measured.
// ---------------------------------------------------------------------------
__global__ __launch_bounds__(256, 4) void flash_attn(
    const bf16* __restrict__ Q, const bf16* __restrict__ K,
    const bf16* __restrict__ Vt, bf16* __restrict__ ctx)
{
  // elements: buf b at b*8192: [K 64x64 | V 64x64] (row stride 64 = 128 B)
  __shared__ bf16 smem[16384];   // 32768 B
  int tid = threadIdx.x;
  int wave = tid >> 6, lane = tid & 63;
  int lm = lane & 15, lq = lane >> 4;
  int x7 = lane & 7;

  int id = blockIdx.x;
  int xcd = id & 7, jj = id >> 3;
  int bh = xcd * 12 + (jj >> 4);
  int q0 = (jj & 15) * 128;

  const bf16* Qb = Q + (size_t)bh * S_ * 64;
  const bf16* Kb = K + (size_t)bh * S_ * 64;
  const bf16* Vb = Vt + (size_t)bh * 64 * S_;

  // staging geometry: chunk = 8 rows x 128 B = 1 KB; lane covers row rr=lane>>3,
  // physical slot lane&7; global fetch slot ls = (lane&7)^rr (inverse swizzle).
  int rr = lane >> 3;
  int ls = (lane & 7) ^ rr;
  const bf16* gk0 = Kb + (size_t)(wave * 16 + rr) * 64 + ls * 8;
  const bf16* gv0 = Vb + (size_t)(wave * 16 + rr) * S_ + ls * 8;

  // ---- prologue: stage Q -> buf1 region, tile0 K/V -> buf0, one full drain.
  {
    const bf16* gq = Qb + (size_t)(q0 + wave * 32 + rr) * 64 + ls * 8;
    #pragma unroll
    for (int c = 0; c < 4; ++c)
      GLD16(gq + (size_t)c * 512, &smem[8192 + (wave * 4 + c) * 512]);
    GLD16(gk0,                    &smem[wave * 1024]);
    GLD16(gk0 + 512,              &smem[wave * 1024 + 512]);
    GLD16(gv0,                    &smem[4096 + wave * 1024]);
    GLD16(gv0 + (size_t)8 * S_,   &smem[4096 + wave * 1024 + 512]);
  }
  __syncthreads();   // vmcnt(0)+lgkm(0)+barrier: Q and tile0 resident

  // hoist qf: Q[q0+qw+mi*16+lm][ks*32+lq*8..+7] via XOR'd slot
  int qw = wave * 32;
  bf16x8 qf[2][2];
  #pragma unroll
  for (int ks = 0; ks < 2; ++ks)
    #pragma unroll
    for (int mi = 0; mi < 2; ++mi)
      qf[ks][mi] = *(const bf16x8*)(&smem[8192 + (qw + mi * 16 + lm) * 64
                                          + ((ks * 4 + lq) ^ x7) * 8]);
  LDS_BARRIER();     // all hoist reads done before tile-1 staging hits buf1

  f32x4 zero = {0.f, 0.f, 0.f, 0.f};
  f32x4 O[2][4];           // O[q = qw+mi*16+lq*4+r][d = dj*16+lm]
  float lsum[2] = {0.f, 0.f};
  #pragma unroll
  for (int i = 0; i < 2; ++i)
    #pragma unroll
    for (int d = 0; d < 4; ++d) O[i][d] = zero;

  for (int t = 0; t < 32; ++t) {
    int cb = (t & 1) << 13;          // current buf base (elems)
    int nb = 8192 - cb;              // next buf base

    // issue tile t+1 staging EARLY (buf[nb]'s readers finished at barrier t-1)
    if (t + 1 < 32) {
      const bf16* gk = gk0 + (size_t)(t + 1) * 4096;   // +64 rows
      const bf16* gv = gv0 + (size_t)(t + 1) * 64;     // +64 cols
      GLD16(gk,                   &smem[nb + wave * 1024]);
      GLD16(gk + 512,             &smem[nb + wave * 1024 + 512]);
      GLD16(gv,                   &smem[nb + 4096 + wave * 1024]);
      GLD16(gv + (size_t)8 * S_,  &smem[nb + 4096 + wave * 1024 + 512]);
    }

    // ---- S^T = K Q^T : sacc[mi][ni] holds S^T[kv=ni*16+lq*4+r][q=qw+mi*16+lm]
    f32x4 sacc[2][4];
    #pragma unroll
    for (int i = 0; i < 2; ++i)
      #pragma unroll
      for (int j = 0; j < 4; ++j) sacc[i][j] = zero;
    __builtin_amdgcn_s_setprio(1);
    #pragma unroll
    for (int ks = 0; ks < 2; ++ks) {
      #pragma unroll
      for (int ni = 0; ni < 4; ++ni) {
        bf16x8 ak = *(const bf16x8*)(&smem[cb + (ni * 16 + lm) * 64
                                           + ((ks * 4 + lq) ^ x7) * 8]);
        sacc[0][ni] = __builtin_amdgcn_mfma_f32_16x16x32_bf16(ak, qf[ks][0], sacc[0][ni], 0, 0, 0);
        sacc[1][ni] = __builtin_amdgcn_mfma_f32_16x16x32_bf16(ak, qf[ks][1], sacc[1][ni], 0, 0, 0);
      }
    }
    __builtin_amdgcn_s_setprio(0);

    // ---- P = exp2(S'): S' already includes log2e via the Q pre-scale
    bf16x4 pexp[2][4];
    #pragma unroll
    for (int mi = 0; mi < 2; ++mi) {
      #pragma unroll
      for (int ni = 0; ni < 4; ++ni) {
        float e0 = EXP2(sacc[mi][ni][0]);
        float e1 = EXP2(sacc[mi][ni][1]);
        float e2 = EXP2(sacc[mi][ni][2]);
        float e3 = EXP2(sacc[mi][ni][3]);
        lsum[mi] += (e0 + e1) + (e2 + e3);
        bf16x4 px = {(bf16)e0, (bf16)e1, (bf16)e2, (bf16)e3};
        pexp[mi][ni] = px;
      }
    }

    // ---- O += P V : A = pexp (regs), B = V^T rows (b64 reads, XOR'd slot)
    __builtin_amdgcn_s_setprio(1);
    #pragma unroll
    for (int ni = 0; ni < 4; ++ni) {
      #pragma unroll
      for (int dj = 0; dj < 4; ++dj) {
        bf16x4 vb = *(const bf16x4*)(&smem[cb + 4096 + (dj * 16 + lm) * 64
                                           + ((ni * 2 + (lq >> 1)) ^ x7) * 8
                                           + (lq & 1) * 4]);
        O[0][dj] = mfma16(pexp[0][ni], vb, O[0][dj]);
        O[1][dj] = mfma16(pexp[1][ni], vb, O[1][dj]);
      }
    }
    __builtin_amdgcn_s_setprio(0);

    // my staging loads landed (latency hidden by the compute above), then
    // LDS-ordered barrier: next iter may read buf[nb] / overwrite buf[cb].
    asm volatile("s_waitcnt vmcnt(0)" ::: "memory");
    LDS_BARRIER();
  }

  // ---- final row-sum reduction: combine the 4 kv-quad groups (lq dim)
  float ls_[2];
  #pragma unroll
  for (int mi = 0; mi < 2; ++mi) {
    float rs = lsum[mi];
    rs += __shfl_xor(rs, 16);
    rs += __shfl_xor(rs, 32);
    ls_[mi] = rs;   // valid for q = qw + mi*16 + lm, all lanes with this lm
  }

  // ---- epilogue: ctx[b][s][h*64+d] = O / l
  int b = bh / H_, h = bh % H_;
  #pragma unroll
  for (int mi = 0; mi < 2; ++mi) {
    #pragma unroll
    for (int r = 0; r < 4; ++r) {
      int s = q0 + qw + mi * 16 + lq * 4 + r;
      float lv = __shfl(ls_[mi], lq * 4 + r);   // held by lane lm' = lq*4+r
      float linv = 1.0f / lv;
      #pragma unroll
      for (int dj = 0; dj < 4; ++dj) {
        int d = dj * 16 + lm;
        ctx[(size_t)(b * S_ + s) * D_ + h * 64 + d] = (bf16)(O[mi][dj][r] * linv);
      }
    }
  }
}

// ---------------------------------------------------------------------------
// Workspace layout (total 104,211,456 B = 99.38 MiB — must stay < 100 MiB):
//   [0      , 1*SZb)  xb   (bf16 x)    — reused as ctx after QKV gemm
//   [1*SZb  , 2*SZb)  Qb
//   [2*SZb  , 3*SZb)  Kb
//   [3*SZb  , 4*SZb)  Vtb
//   [4*SZb  , +3.54M) Wt [2304][768]   — dead after gemm_bt<1>; Wpt aliases it
//   [.. +9216)        ball (2304 f32)
// Wpt's transpose is launched AFTER gemm_bt<1> (stream-ordered), so aliasing
// Wpt onto Wt is safe and keeps the footprint under the workspace size.
// ---------------------------------------------------------------------------
extern "C" void kernel_launch(void* const* d_in, const int* in_sizes, int n_in,
                              void* d_out, int out_size, void* d_ws, size_t ws_size,
                              hipStream_t stream)
{
  const float* x  = (const float*)d_in[0];
  const float* Wq = (const float*)d_in[1];
  const float* bq = (const float*)d_in[2];
  const float* Wk = (const float*)d_in[3];
  const float* bk = (const float*)d_in[4];
  const float* Wv = (const float*)d_in[5];
  const float* bv = (const float*)d_in[6];
  const float* Wp = (const float*)d_in[7];
  const float* bp = (const float*)d_in[8];
  float* out = (float*)d_out;

  char* w = (char*)d_ws;
  const size_t SZ  = (size_t)BH_ * S_ * 64;   // 12,582,912 elems
  const size_t SZb = SZ * sizeof(bf16);       // 25,165,824 bytes
  bf16*  xb   = (bf16*)(w);                   // also reused as ctx
  bf16*  Qb   = (bf16*)(w + 1 * SZb);
  bf16*  Kb   = (bf16*)(w + 2 * SZb);
  bf16*  Vtb  = (bf16*)(w + 3 * SZb);
  bf16*  Wt   = (bf16*)(w + 4 * SZb);                       // [2304][768] bf16
  bf16*  Wpt  = Wt;   // aliases Wt: written after gemm_bt<1>, when Wt is dead
  float* ball = (float*)(w + 4 * SZb + 2304 * 768 * 2);
  bf16*  ctx  = xb;  // xb's last reader (QKV gemm) precedes flash_attn on stream

  // prep: x->bf16, fused {Wq|Wk|Wv transpose + bias pack}
  f2b<<<(int)(SZ / (256 * 8)), 256, 0, stream>>>(x, xb, (int)SZ);
  prep_w<<<dim3(12, 1, 37), 256, 0, stream>>>(Wq, Wk, Wv, bq, bk, bv, Wt, ball);

  // QKV projection -> Q(scaled)/K [B,H,S,64], V -> V^T [bh][64][S] (+bias)
  gemm_bt<1><<<dim3(128, 18), 256, 0, stream>>>(xb, Wt, ball, (float*)nullptr,
                                                Qb, Kb, Vtb, M_, 2304, 768);
  // Wp transpose AFTER Wt's last reader — Wpt aliases Wt's storage
  transpose64_f2b<<<dim3(12, 12, 1), 256, 0, stream>>>(Wp, Wpt, 768, 768);
  // attention (1536 blocks, XCD-swizzled decode inside)
  flash_attn<<<1536, 256, 0, stream>>>(Qb, Kb, Vtb, ctx);
  // output projection -> fp32 out
  gemm_bt<0><<<dim3(128, 6), 256, 0, stream>>>(ctx, Wpt, bp, out,
                                               (bf16*)nullptr, (bf16*)nullptr, (bf16*)nullptr,
                                               M_, 768, 768);
}

// Round 11
// 359.994 us; speedup vs baseline: 1.0638x; 1.0638x over previous
//
#include <hip/hip_runtime.h>
#include <hip/hip_bf16.h>
#include <stdint.h>

// Problem constants
#define B_  8
#define S_  2048
#define D_  768
#define H_  12
#define HD_ 64
#define BH_ (B_*H_)   // 96
#define M_  (B_*S_)   // 16384

typedef __bf16 bf16;
typedef __bf16 bf16x8 __attribute__((ext_vector_type(8)));
typedef __bf16 bf16x4 __attribute__((ext_vector_type(4)));
typedef short  short4v __attribute__((ext_vector_type(4)));
typedef float  f32x4  __attribute__((ext_vector_type(4)));

// Q pre-scale folds log2(e) so softmax uses native exp2 (v_exp_f32 IS exp2):
// 1/(8+1e-6) * log2(e); exp2(S*log2e) == exp(S).
#define QSCALE2 0.18033685756901243f

#if __has_builtin(__builtin_amdgcn_exp2f)
#define EXP2(x) __builtin_amdgcn_exp2f(x)
#else
#define EXP2(x) exp2f(x)
#endif

// LDS-only barrier: orders ds ops across the workgroup WITHOUT draining vmcnt.
#define LDS_BARRIER() asm volatile("s_waitcnt lgkmcnt(0)\n\ts_barrier" ::: "memory")

// global -> LDS direct copy, 16 B per lane (dest = uniform base + lane*16).
#define GLD16(gptr, lptr) __builtin_amdgcn_global_load_lds( \
    (const __attribute__((address_space(1))) uint32_t*)(gptr), \
    (__attribute__((address_space(3))) uint32_t*)(lptr), 16, 0, 0)

// 16x16x16 bf16 MFMA: A-layout == C/D-layout-transposed, the key identity.
#if __has_builtin(__builtin_amdgcn_mfma_f32_16x16x16bf16_1k)
static __device__ inline f32x4 mfma16(bf16x4 a, bf16x4 b, f32x4 c) {
  return __builtin_amdgcn_mfma_f32_16x16x16bf16_1k(
      __builtin_bit_cast(short4v, a), __builtin_bit_cast(short4v, b), c, 0, 0, 0);
}
#else
// fallback: zero-pad halves into the known-good 16x16x32 (same result)
static __device__ inline f32x4 mfma16(bf16x4 a, bf16x4 b, f32x4 c) {
  bf16 z = (bf16)0.f;
  bf16x8 a8 = {a[0], a[1], a[2], a[3], z, z, z, z};
  bf16x8 b8 = {b[0], b[1], b[2], b[3], z, z, z, z};
  return __builtin_amdgcn_mfma_f32_16x16x32_bf16(a8, b8, c, 0, 0, 0);
}
#endif

// ---------------------------------------------------------------------------
// fp32 -> bf16 elementwise convert, 8 elems/thread
// ---------------------------------------------------------------------------
__global__ __launch_bounds__(256) void f2b(const float* __restrict__ src,
                                           bf16* __restrict__ dst, int n) {
  int i = (blockIdx.x * 256 + threadIdx.x) * 8;
  if (i >= n) return;
  float4 a = *(const float4*)(src + i);
  float4 b = *(const float4*)(src + i + 4);
  bf16 o[8] = {(bf16)a.x, (bf16)a.y, (bf16)a.z, (bf16)a.w,
               (bf16)b.x, (bf16)b.y, (bf16)b.z, (bf16)b.w};
  *(uint4*)(dst + i) = *(const uint4*)o;
}

// ---------------------------------------------------------------------------
// 64x64-tile transpose + fp32->bf16: src f32 [mat][R][C] -> dst bf16 [mat][C][R]
// (still used for Wp)
// ---------------------------------------------------------------------------
__global__ __launch_bounds__(256) void transpose64_f2b(const float* __restrict__ src,
                                                       bf16* __restrict__ dst,
                                                       int R, int C) {
  __shared__ bf16 t[64][72];
  int mat = blockIdx.z;
  const float* s = src + (size_t)mat * R * C;
  bf16* d = dst + (size_t)mat * C * R;
  int r0 = blockIdx.x * 64, c0 = blockIdx.y * 64;
  int tid = threadIdx.x;
  #pragma unroll
  for (int it = 0; it < 4; ++it) {
    int i = (tid >> 4) + it * 16;
    int j = (tid & 15) * 4;
    float4 v = *(const float4*)(s + (size_t)(r0 + i) * C + c0 + j);
    t[j + 0][i] = (bf16)v.x; t[j + 1][i] = (bf16)v.y;
    t[j + 2][i] = (bf16)v.z; t[j + 3][i] = (bf16)v.w;
  }
  __syncthreads();
  #pragma unroll
  for (int it = 0; it < 4; ++it) {
    int i = (tid >> 4) + it * 16;
    int j = (tid & 15) * 4;
    bf16* p = d + (size_t)(c0 + i) * R + r0 + j;
    p[0] = t[i][j]; p[1] = t[i][j + 1]; p[2] = t[i][j + 2]; p[3] = t[i][j + 3];
  }
}

// ---------------------------------------------------------------------------
// Fused prep: transpose Wq|Wk|Wv (36 head-tiles of [768][64] -> [64][768])
// into Wt[2304][768], plus bias packing (z==36). Replaces 4 launches with 1.
// ---------------------------------------------------------------------------
__global__ __launch_bounds__(256) void prep_w(
    const float* __restrict__ Wq, const float* __restrict__ Wk,
    const float* __restrict__ Wv, const float* __restrict__ bq,
    const float* __restrict__ bk, const float* __restrict__ bv,
    bf16* __restrict__ Wt, float* __restrict__ ball)
{
  int z = blockIdx.z;
  int tid = threadIdx.x;
  if (z == 36) {   // bias pack: 12 blocks x 256 threads >= 2304
    int i = blockIdx.x * 256 + tid;
    if (i < 2304) {
      float v = (i < 768) ? bq[i] : (i < 1536 ? bk[i - 768] : bv[i - 1536]);
      ball[i] = v;
    }
    return;
  }
  __shared__ bf16 t[64][72];
  int w = z / 12, h = z % 12;
  const float* s = (w == 0 ? Wq : (w == 1 ? Wk : Wv)) + (size_t)h * 768 * 64;
  bf16* d = Wt + (size_t)z * 64 * 768;          // [64][768] head-tile
  int r0 = blockIdx.x * 64;                      // over R=768
  #pragma unroll
  for (int it = 0; it < 4; ++it) {
    int i = (tid >> 4) + it * 16;
    int j = (tid & 15) * 4;
    float4 v = *(const float4*)(s + (size_t)(r0 + i) * 64 + j);
    t[j + 0][i] = (bf16)v.x; t[j + 1][i] = (bf16)v.y;
    t[j + 2][i] = (bf16)v.z; t[j + 3][i] = (bf16)v.w;
  }
  __syncthreads();
  #pragma unroll
  for (int it = 0; it < 4; ++it) {
    int i = (tid >> 4) + it * 16;
    int j = (tid & 15) * 4;
    bf16* p = d + (size_t)i * 768 + r0 + j;
    p[0] = t[i][j]; p[1] = t[i][j + 1]; p[2] = t[i][j + 2]; p[3] = t[i][j + 3];
  }
}

// ---------------------------------------------------------------------------
// GEMM: C[M,N] = A[M,K](bf16) * Bt[N,K]^T(bf16) + bias[N](fp32)
// 128x128 tile, BK=32, 256 threads (4 waves, 2x2), mfma_f32_16x16x32_bf16.
// ASYNC ping-pong staging (r8 flash recipe). __launch_bounds__(256,3):
// reg cap 170 (live set ~130: 64 acc AGPR + 32 frag + ~30 addr — no spill,
// unlike (256,4)'s 128 cap which shaved into scratch, r10 -14us) while
// forcing 3 blocks/CU (96KB LDS) = 12 waves/CU TLP vs (256,2)'s 8.
// Rule-#21 swizzle: linear LDS dest, inverse-XOR'd global source, same XOR
// on ds_read (slot ^= row&3 within 64B rows).
// MODE 0: fp32 row-major C. MODE 1: scatter Q (pre-scaled)/K to [B,H,S,64]
//         and V to V^T layout [bh][64][S] (bf16), all with bias.
// ---------------------------------------------------------------------------
template <int MODE>
__global__ __launch_bounds__(256, 3) void gemm_bt(
    const bf16* __restrict__ A, const bf16* __restrict__ Bt,
    const float* __restrict__ bias, float* __restrict__ C,
    bf16* __restrict__ Qo, bf16* __restrict__ Ko, bf16* __restrict__ Vo,
    int Mdim, int Ndim, int Kdim)
{
  // buf b at b*8192 elems: [As 4096 | Bs 4096]; 32 KB total
  __shared__ bf16 smem[16384];
  int tid = threadIdx.x;
  int wave = tid >> 6, lane = tid & 63;
  int wm = wave & 1, wn = wave >> 1;
  int m0 = blockIdx.x * 128, n0 = blockIdx.y * 128;
  int lm = lane & 15, lq = lane >> 4;

  int c0_ = wave * 2;
  int r_in = lane >> 2;                     // 0..15
  int ps   = lane & 3;                      // physical 16B slot in 64B row
  int rowA0 = c0_ * 16 + r_in;              // chunk 2w row
  int rowA1 = rowA0 + 16;                   // chunk 2w+1 row
  int ls0 = ps ^ (rowA0 & 3);               // logical slot (inverse swizzle)
  int ls1 = ps ^ (rowA1 & 3);

  f32x4 zero = {0.f, 0.f, 0.f, 0.f};
  f32x4 acc[4][4];
  #pragma unroll
  for (int i = 0; i < 4; ++i)
    #pragma unroll
    for (int j = 0; j < 4; ++j) acc[i][j] = zero;

  int NK = Kdim >> 5;

  // prologue: stage k=0 into buf0, full drain
  GLD16(A  + (size_t)(m0 + rowA0) * Kdim + ls0 * 8, &smem[c0_ * 512]);
  GLD16(A  + (size_t)(m0 + rowA1) * Kdim + ls1 * 8, &smem[c0_ * 512 + 512]);
  GLD16(Bt + (size_t)(n0 + rowA0) * Kdim + ls0 * 8, &smem[4096 + c0_ * 512]);
  GLD16(Bt + (size_t)(n0 + rowA1) * Kdim + ls1 * 8, &smem[4096 + c0_ * 512 + 512]);
  __syncthreads();   // vmcnt(0)+lgkm(0)+barrier: tile 0 resident

  for (int kk = 0; kk < NK; ++kk) {
    int cb = (kk & 1) << 13;   // current buf base (elems)
    int nb = 8192 - cb;        // next buf base

    if (kk + 1 < NK) {         // issue tile kk+1 staging EARLY
      int k0 = (kk + 1) * 32;
      GLD16(A  + (size_t)(m0 + rowA0) * Kdim + k0 + ls0 * 8, &smem[nb + c0_ * 512]);
      GLD16(A  + (size_t)(m0 + rowA1) * Kdim + k0 + ls1 * 8, &smem[nb + c0_ * 512 + 512]);
      GLD16(Bt + (size_t)(n0 + rowA0) * Kdim + k0 + ls0 * 8, &smem[nb + 4096 + c0_ * 512]);
      GLD16(Bt + (size_t)(n0 + rowA1) * Kdim + k0 + ls1 * 8, &smem[nb + 4096 + c0_ * 512 + 512]);
    }

    bf16x8 af[4], bfr[4];
    #pragma unroll
    for (int i = 0; i < 4; ++i) {
      int ra = wm * 64 + i * 16 + lm;
      af[i] = *(const bf16x8*)(&smem[cb + ra * 32 + ((lq ^ (ra & 3)) * 8)]);
    }
    #pragma unroll
    for (int j = 0; j < 4; ++j) {
      int rb = wn * 64 + j * 16 + lm;
      bfr[j] = *(const bf16x8*)(&smem[cb + 4096 + rb * 32 + ((lq ^ (rb & 3)) * 8)]);
    }
    __builtin_amdgcn_s_setprio(1);
    #pragma unroll
    for (int i = 0; i < 4; ++i)
      #pragma unroll
      for (int j = 0; j < 4; ++j)
        acc[i][j] = __builtin_amdgcn_mfma_f32_16x16x32_bf16(af[i], bfr[j], acc[i][j], 0, 0, 0);
    __builtin_amdgcn_s_setprio(0);

    // staging loads landed (hidden under the MFMAs), then LDS-ordered barrier
    asm volatile("s_waitcnt vmcnt(0)" ::: "memory");
    LDS_BARRIER();
  }

  int mbase = m0 + wm * 64, nbase = n0 + wn * 64;
  #pragma unroll
  for (int j = 0; j < 4; ++j) {
    int n = nbase + j * 16 + lm;
    float bv_ = bias[n];
    if (MODE == 0) {
      #pragma unroll
      for (int i = 0; i < 4; ++i)
        #pragma unroll
        for (int r = 0; r < 4; ++r) {
          int m = mbase + i * 16 + lq * 4 + r;
          C[(size_t)m * Ndim + n] = acc[i][j][r] + bv_;
        }
    } else {
      int which = n / 768;             // uniform per block (768 = 6*128)
      int rem = n - which * 768;
      int h = rem >> 6, e = rem & 63;
      float scl = (which == 0) ? QSCALE2 : 1.0f;
      if (which == 2) {
        #pragma unroll
        for (int i = 0; i < 4; ++i)
          #pragma unroll
          for (int r = 0; r < 4; ++r) {
            int m = mbase + i * 16 + lq * 4 + r;
            int b = m >> 11, s = m & 2047;
            Vo[((size_t)(b * H_ + h) * 64 + e) * S_ + s] = (bf16)(acc[i][j][r] + bv_);
          }
      } else {
        bf16* dst = (which == 0) ? Qo : Ko;
        #pragma unroll
        for (int i = 0; i < 4; ++i)
          #pragma unroll
          for (int r = 0; r < 4; ++r) {
            int m = mbase + i * 16 + lq * 4 + r;
            int b = m >> 11, s = m & 2047;
            dst[((size_t)(b * H_ + h) * S_ + s) * 64 + e] = (bf16)((acc[i][j][r] + bv_) * scl);
          }
      }
    }
  }
}

// ---------------------------------------------------------------------------
// Flash attention v2 (r8 winner, UNTOUCHED): global_load_lds K/V staging,
// ping-pong LDS, issue-early/drain-late, 1 barrier/iter, rule-#21 swizzle,
// setprio around MFMA clusters. 153.7 us measured.
// ---------------------------------------------------------------------------
__global__ __launch_bounds__(256, 4) void flash_attn(
    const bf16* __restrict__ Q, const bf16* __restrict__ K,
    const bf16* __restrict__ Vt, bf16* __restrict__ ctx)
{
  // elements: buf b at b*8192: [K 64x64 | V 64x64] (row stride 64 = 128 B)
  __shared__ bf16 smem[16384];   // 32768 B
  int tid = threadIdx.x;
  int wave = tid >> 6, lane = tid & 63;
  int lm = lane & 15, lq = lane >> 4;
  int x7 = lane & 7;

  int id = blockIdx.x;
  int xcd = id & 7, jj = id >> 3;
  int bh = xcd * 12 + (jj >> 4);
  int q0 = (jj & 15) * 128;

  const bf16* Qb = Q + (size_t)bh * S_ * 64;
  const bf16* Kb = K + (size_t)bh * S_ * 64;
  const bf16* Vb = Vt + (size_t)bh * 64 * S_;

  // staging geometry: chunk = 8 rows x 128 B = 1 KB; lane covers row rr=lane>>3,
  // physical slot lane&7; global fetch slot ls = (lane&7)^rr (inverse swizzle).
  int rr = lane >> 3;
  int ls = (lane & 7) ^ rr;
  const bf16* gk0 = Kb + (size_t)(wave * 16 + rr) * 64 + ls * 8;
  const bf16* gv0 = Vb + (size_t)(wave * 16 + rr) * S_ + ls * 8;

  // ---- prologue: stage Q -> buf1 region, tile0 K/V -> buf0, one full drain.
  {
    const bf16* gq = Qb + (size_t)(q0 + wave * 32 + rr) * 64 + ls * 8;
    #pragma unroll
    for (int c = 0; c < 4; ++c)
      GLD16(gq + (size_t)c * 512, &smem[8192 + (wave * 4 + c) * 512]);
    GLD16(gk0,                    &smem[wave * 1024]);
    GLD16(gk0 + 512,              &smem[wave * 1024 + 512]);
    GLD16(gv0,                    &smem[4096 + wave * 1024]);
    GLD16(gv0 + (size_t)8 * S_,   &smem[4096 + wave * 1024 + 512]);
  }
  __syncthreads();   // vmcnt(0)+lgkm(0)+barrier: Q and tile0 resident

  // hoist qf: Q[q0+qw+mi*16+lm][ks*32+lq*8..+7] via XOR'd slot
  int qw = wave * 32;
  bf16x8 qf[2][2];
  #pragma unroll
  for (int ks = 0; ks < 2; ++ks)
    #pragma unroll
    for (int mi = 0; mi < 2; ++mi)
      qf[ks][mi] = *(const bf16x8*)(&smem[8192 + (qw + mi * 16 + lm) * 64
                                          + ((ks * 4 + lq) ^ x7) * 8]);
  LDS_BARRIER();     // all hoist reads done before tile-1 staging hits buf1

  f32x4 zero = {0.f, 0.f, 0.f, 0.f};
  f32x4 O[2][4];           // O[q = qw+mi*16+lq*4+r][d = dj*16+lm]
  float lsum[2] = {0.f, 0.f};
  #pragma unroll
  for (int i = 0; i < 2; ++i)
    #pragma unroll
    for (int d = 0; d < 4; ++d) O[i][d] = zero;

  for (int t = 0; t < 32; ++t) {
    int cb = (t & 1) << 13;          // current buf base (elems)
    int nb = 8192 - cb;              // next buf base

    // issue tile t+1 staging EARLY (buf[nb]'s readers finished at barrier t-1)
    if (t + 1 < 32) {
      const bf16* gk = gk0 + (size_t)(t + 1) * 4096;   // +64 rows
      const bf16* gv = gv0 + (size_t)(t + 1) * 64;     // +64 cols
      GLD16(gk,                   &smem[nb + wave * 1024]);
      GLD16(gk + 512,             &smem[nb + wave * 1024 + 512]);
      GLD16(gv,                   &smem[nb + 4096 + wave * 1024]);
      GLD16(gv + (size_t)8 * S_,  &smem[nb + 4096 + wave * 1024 + 512]);
    }

    // ---- S^T = K Q^T : sacc[mi][ni] holds S^T[kv=ni*16+lq*4+r][q=qw+mi*16+lm]
    f32x4 sacc[2][4];
    #pragma unroll
    for (int i = 0; i < 2; ++i)
      #pragma unroll
      for (int j = 0; j < 4; ++j) sacc[i][j] = zero;
    __builtin_amdgcn_s_setprio(1);
    #pragma unroll
    for (int ks = 0; ks < 2; ++ks) {
      #pragma unroll
      for (int ni = 0; ni < 4; ++ni) {
        bf16x8 ak = *(const bf16x8*)(&smem[cb + (ni * 16 + lm) * 64
                                           + ((ks * 4 + lq) ^ x7) * 8]);
        sacc[0][ni] = __builtin_amdgcn_mfma_f32_16x16x32_bf16(ak, qf[ks][0], sacc[0][ni], 0, 0, 0);
        sacc[1][ni] = __builtin_amdgcn_mfma_f32_16x16x32_bf16(ak, qf[ks][1], sacc[1][ni], 0, 0, 0);
      }
    }
    __builtin_amdgcn_s_setprio(0);

    // ---- P = exp2(S'): S' already includes log2e via the Q pre-scale
    bf16x4 pexp[2][4];
    #pragma unroll
    for (int mi = 0; mi < 2; ++mi) {
      #pragma unroll
      for (int ni = 0; ni < 4; ++ni) {
        float e0 = EXP2(sacc[mi][ni][0]);
        float e1 = EXP2(sacc[mi][ni][1]);
        float e2 = EXP2(sacc[mi][ni][2]);
        float e3 = EXP2(sacc[mi][ni][3]);
        lsum[mi] += (e0 + e1) + (e2 + e3);
        bf16x4 px = {(bf16)e0, (bf16)e1, (bf16)e2, (bf16)e3};
        pexp[mi][ni] = px;
      }
    }

    // ---- O += P V : A = pexp (regs), B = V^T rows (b64 reads, XOR'd slot)
    __builtin_amdgcn_s_setprio(1);
    #pragma unroll
    for (int ni = 0; ni < 4; ++ni) {
      #pragma unroll
      for (int dj = 0; dj < 4; ++dj) {
        bf16x4 vb = *(const bf16x4*)(&smem[cb + 4096 + (dj * 16 + lm) * 64
                                           + ((ni * 2 + (lq >> 1)) ^ x7) * 8
                                           + (lq & 1) * 4]);
        O[0][dj] = mfma16(pexp[0][ni], vb, O[0][dj]);
        O[1][dj] = mfma16(pexp[1][ni], vb, O[1][dj]);
      }
    }
    __builtin_amdgcn_s_setprio(0);

    // my staging loads landed (latency hidden by the compute above), then
    // LDS-ordered barrier: next iter may read buf[nb] / overwrite buf[cb].
    asm volatile("s_waitcnt vmcnt(0)" ::: "memory");
    LDS_BARRIER();
  }

  // ---- final row-sum reduction: combine the 4 kv-quad groups (lq dim)
  float ls_[2];
  #pragma unroll
  for (int mi = 0; mi < 2; ++mi) {
    float rs = lsum[mi];
    rs += __shfl_xor(rs, 16);
    rs += __shfl_xor(rs, 32);
    ls_[mi] = rs;   // valid for q = qw + mi*16 + lm, all lanes with this lm
  }

  // ---- epilogue: ctx[b][s][h*64+d] = O / l
  int b = bh / H_, h = bh % H_;
  #pragma unroll
  for (int mi = 0; mi < 2; ++mi) {
    #pragma unroll
    for (int r = 0; r < 4; ++r) {
      int s = q0 + qw + mi * 16 + lq * 4 + r;
      float lv = __shfl(ls_[mi], lq * 4 + r);   // held by lane lm' = lq*4+r
      float linv = 1.0f / lv;
      #pragma unroll
      for (int dj = 0; dj < 4; ++dj) {
        int d = dj * 16 + lm;
        ctx[(size_t)(b * S_ + s) * D_ + h * 64 + d] = (bf16)(O[mi][dj][r] * linv);
      }
    }
  }
}

// ---------------------------------------------------------------------------
// Workspace layout (total 104,211,456 B = 99.38 MiB — must stay < 100 MiB):
//   [0      , 1*SZb)  xb   (bf16 x)    — reused as ctx after QKV gemm
//   [1*SZb  , 2*SZb)  Qb
//   [2*SZb  , 3*SZb)  Kb
//   [3*SZb  , 4*SZb)  Vtb
//   [4*SZb  , +3.54M) Wt [2304][768]   — dead after gemm_bt<1>; Wpt aliases it
//   [.. +9216)        ball (2304 f32)
// Wpt's transpose is launched AFTER gemm_bt<1> (stream-ordered), so aliasing
// Wpt onto Wt is safe and keeps the footprint under the workspace size.
// ---------------------------------------------------------------------------
extern "C" void kernel_launch(void* const* d_in, const int* in_sizes, int n_in,
                              void* d_out, int out_size, void* d_ws, size_t ws_size,
                              hipStream_t stream)
{
  const float* x  = (const float*)d_in[0];
  const float* Wq = (const float*)d_in[1];
  const float* bq = (const float*)d_in[2];
  const float* Wk = (const float*)d_in[3];
  const float* bk = (const float*)d_in[4];
  const float* Wv = (const float*)d_in[5];
  const float* bv = (const float*)d_in[6];
  const float* Wp = (const float*)d_in[7];
  const float* bp = (const float*)d_in[8];
  float* out = (float*)d_out;

  char* w = (char*)d_ws;
  const size_t SZ  = (size_t)BH_ * S_ * 64;   // 12,582,912 elems
  const size_t SZb = SZ * sizeof(bf16);       // 25,165,824 bytes
  bf16*  xb   = (bf16*)(w);                   // also reused as ctx
  bf16*  Qb   = (bf16*)(w + 1 * SZb);
  bf16*  Kb   = (bf16*)(w + 2 * SZb);
  bf16*  Vtb  = (bf16*)(w + 3 * SZb);
  bf16*  Wt   = (bf16*)(w + 4 * SZb);                       // [2304][768] bf16
  bf16*  Wpt  = Wt;   // aliases Wt: written after gemm_bt<1>, when Wt is dead
  float* ball = (float*)(w + 4 * SZb + 2304 * 768 * 2);
  bf16*  ctx  = xb;  // xb's last reader (QKV gemm) precedes flash_attn on stream

  // prep: x->bf16, fused {Wq|Wk|Wv transpose + bias pack}
  f2b<<<(int)(SZ / (256 * 8)), 256, 0, stream>>>(x, xb, (int)SZ);
  prep_w<<<dim3(12, 1, 37), 256, 0, stream>>>(Wq, Wk, Wv, bq, bk, bv, Wt, ball);

  // QKV projection -> Q(scaled)/K [B,H,S,64], V -> V^T [bh][64][S] (+bias)
  gemm_bt<1><<<dim3(128, 18), 256, 0, stream>>>(xb, Wt, ball, (float*)nullptr,
                                                Qb, Kb, Vtb, M_, 2304, 768);
  // Wp transpose AFTER Wt's last reader — Wpt aliases Wt's storage
  transpose64_f2b<<<dim3(12, 12, 1), 256, 0, stream>>>(Wp, Wpt, 768, 768);
  // attention (1536 blocks, XCD-swizzled decode inside)
  flash_attn<<<1536, 256, 0, stream>>>(Qb, Kb, Vtb, ctx);
  // output projection -> fp32 out
  gemm_bt<0><<<dim3(128, 6), 256, 0, stream>>>(ctx, Wpt, bp, out,
                                               (bf16*)nullptr, (bf16*)nullptr, (bf16*)nullptr,
                                               M_, 768, 768);
}

// Round 12
// 355.751 us; speedup vs baseline: 1.0765x; 1.0119x over previous
//
#include <hip/hip_runtime.h>
#include <hip/hip_bf16.h>
#include <stdint.h>

// Problem constants
#define B_  8
#define S_  2048
#define D_  768
#define H_  12
#define HD_ 64
#define BH_ (B_*H_)   // 96
#define M_  (B_*S_)   // 16384

typedef __bf16 bf16;
typedef __bf16 bf16x8 __attribute__((ext_vector_type(8)));
typedef __bf16 bf16x4 __attribute__((ext_vector_type(4)));
typedef short  short4v __attribute__((ext_vector_type(4)));
typedef float  f32x4  __attribute__((ext_vector_type(4)));

// Q pre-scale folds log2(e) so softmax uses native exp2 (v_exp_f32 IS exp2):
// 1/(8+1e-6) * log2(e); exp2(S*log2e) == exp(S).
#define QSCALE2 0.18033685756901243f

#if __has_builtin(__builtin_amdgcn_exp2f)
#define EXP2(x) __builtin_amdgcn_exp2f(x)
#else
#define EXP2(x) exp2f(x)
#endif

// LDS-only barrier: orders ds ops across the workgroup WITHOUT draining vmcnt.
#define LDS_BARRIER() asm volatile("s_waitcnt lgkmcnt(0)\n\ts_barrier" ::: "memory")

// global -> LDS direct copy, 16 B per lane (dest = uniform base + lane*16).
#define GLD16(gptr, lptr) __builtin_amdgcn_global_load_lds( \
    (const __attribute__((address_space(1))) uint32_t*)(gptr), \
    (__attribute__((address_space(3))) uint32_t*)(lptr), 16, 0, 0)

// 16x16x16 bf16 MFMA: A-layout == C/D-layout-transposed, the key identity.
#if __has_builtin(__builtin_amdgcn_mfma_f32_16x16x16bf16_1k)
static __device__ inline f32x4 mfma16(bf16x4 a, bf16x4 b, f32x4 c) {
  return __builtin_amdgcn_mfma_f32_16x16x16bf16_1k(
      __builtin_bit_cast(short4v, a), __builtin_bit_cast(short4v, b), c, 0, 0, 0);
}
#else
// fallback: zero-pad halves into the known-good 16x16x32 (same result)
static __device__ inline f32x4 mfma16(bf16x4 a, bf16x4 b, f32x4 c) {
  bf16 z = (bf16)0.f;
  bf16x8 a8 = {a[0], a[1], a[2], a[3], z, z, z, z};
  bf16x8 b8 = {b[0], b[1], b[2], b[3], z, z, z, z};
  return __builtin_amdgcn_mfma_f32_16x16x32_bf16(a8, b8, c, 0, 0, 0);
}
#endif

// ---------------------------------------------------------------------------
// fp32 -> bf16 elementwise convert, 8 elems/thread
// ---------------------------------------------------------------------------
__global__ __launch_bounds__(256) void f2b(const float* __restrict__ src,
                                           bf16* __restrict__ dst, int n) {
  int i = (blockIdx.x * 256 + threadIdx.x) * 8;
  if (i >= n) return;
  float4 a = *(const float4*)(src + i);
  float4 b = *(const float4*)(src + i + 4);
  bf16 o[8] = {(bf16)a.x, (bf16)a.y, (bf16)a.z, (bf16)a.w,
               (bf16)b.x, (bf16)b.y, (bf16)b.z, (bf16)b.w};
  *(uint4*)(dst + i) = *(const uint4*)o;
}

// ---------------------------------------------------------------------------
// 64x64-tile transpose + fp32->bf16: src f32 [mat][R][C] -> dst bf16 [mat][C][R]
// (still used for Wp)
// ---------------------------------------------------------------------------
__global__ __launch_bounds__(256) void transpose64_f2b(const float* __restrict__ src,
                                                       bf16* __restrict__ dst,
                                                       int R, int C) {
  __shared__ bf16 t[64][72];
  int mat = blockIdx.z;
  const float* s = src + (size_t)mat * R * C;
  bf16* d = dst + (size_t)mat * C * R;
  int r0 = blockIdx.x * 64, c0 = blockIdx.y * 64;
  int tid = threadIdx.x;
  #pragma unroll
  for (int it = 0; it < 4; ++it) {
    int i = (tid >> 4) + it * 16;
    int j = (tid & 15) * 4;
    float4 v = *(const float4*)(s + (size_t)(r0 + i) * C + c0 + j);
    t[j + 0][i] = (bf16)v.x; t[j + 1][i] = (bf16)v.y;
    t[j + 2][i] = (bf16)v.z; t[j + 3][i] = (bf16)v.w;
  }
  __syncthreads();
  #pragma unroll
  for (int it = 0; it < 4; ++it) {
    int i = (tid >> 4) + it * 16;
    int j = (tid & 15) * 4;
    bf16* p = d + (size_t)(c0 + i) * R + r0 + j;
    p[0] = t[i][j]; p[1] = t[i][j + 1]; p[2] = t[i][j + 2]; p[3] = t[i][j + 3];
  }
}

// ---------------------------------------------------------------------------
// Fused prep: transpose Wq|Wk|Wv (36 head-tiles of [768][64] -> [64][768])
// into Wt[2304][768], plus bias packing (z==36). Replaces 4 launches with 1.
// ---------------------------------------------------------------------------
__global__ __launch_bounds__(256) void prep_w(
    const float* __restrict__ Wq, const float* __restrict__ Wk,
    const float* __restrict__ Wv, const float* __restrict__ bq,
    const float* __restrict__ bk, const float* __restrict__ bv,
    bf16* __restrict__ Wt, float* __restrict__ ball)
{
  int z = blockIdx.z;
  int tid = threadIdx.x;
  if (z == 36) {   // bias pack: 12 blocks x 256 threads >= 2304
    int i = blockIdx.x * 256 + tid;
    if (i < 2304) {
      float v = (i < 768) ? bq[i] : (i < 1536 ? bk[i - 768] : bv[i - 1536]);
      ball[i] = v;
    }
    return;
  }
  __shared__ bf16 t[64][72];
  int w = z / 12, h = z % 12;
  const float* s = (w == 0 ? Wq : (w == 1 ? Wk : Wv)) + (size_t)h * 768 * 64;
  bf16* d = Wt + (size_t)z * 64 * 768;          // [64][768] head-tile
  int r0 = blockIdx.x * 64;                      // over R=768
  #pragma unroll
  for (int it = 0; it < 4; ++it) {
    int i = (tid >> 4) + it * 16;
    int j = (tid & 15) * 4;
    float4 v = *(const float4*)(s + (size_t)(r0 + i) * 64 + j);
    t[j + 0][i] = (bf16)v.x; t[j + 1][i] = (bf16)v.y;
    t[j + 2][i] = (bf16)v.z; t[j + 3][i] = (bf16)v.w;
  }
  __syncthreads();
  #pragma unroll
  for (int it = 0; it < 4; ++it) {
    int i = (tid >> 4) + it * 16;
    int j = (tid & 15) * 4;
    bf16* p = d + (size_t)i * 768 + r0 + j;
    p[0] = t[i][j]; p[1] = t[i][j + 1]; p[2] = t[i][j + 2]; p[3] = t[i][j + 3];
  }
}

// ---------------------------------------------------------------------------
// GEMM: C[M,N] = A[M,K](bf16) * Bt[N,K]^T(bf16) + bias[N](fp32)
// 128x128 tile, BK=32, 256 threads (4 waves, 2x2), mfma_f32_16x16x32_bf16.
// DISTANCE-2 async pipeline (T4 counted-vmcnt): 3 LDS buffers rotate;
// iter kk issues tile kk+2's global_load_lds, computes tile kk, then waits
// vmcnt(4) — retiring exactly tile kk+1 (4 loads/wave/tile) while kk+2's
// stay in flight. Each load gets ~2 iterations (~400-500 cyc) to cover
// L2/queueing latency (distance-1's ~200 cyc window was short, r11 +9us
// from TLP alone). Tail degrades to vmcnt(0) when nothing new is issued.
// __launch_bounds__(256,3): reg cap 170 (no spill), 3 blocks/CU x 48 KB
// = 144 KB LDS. Rule-#21 swizzle as before.
// MODE 0: fp32 row-major C. MODE 1: scatter Q (pre-scaled)/K to [B,H,S,64]
//         and V to V^T layout [bh][64][S] (bf16), all with bias.
// ---------------------------------------------------------------------------
template <int MODE>
__global__ __launch_bounds__(256, 3) void gemm_bt(
    const bf16* __restrict__ A, const bf16* __restrict__ Bt,
    const float* __restrict__ bias, float* __restrict__ C,
    bf16* __restrict__ Qo, bf16* __restrict__ Ko, bf16* __restrict__ Vo,
    int Mdim, int Ndim, int Kdim)
{
  // buf b at b*8192 elems: [As 4096 | Bs 4096]; 3 bufs, 48 KB total
  __shared__ bf16 smem[24576];
  int tid = threadIdx.x;
  int wave = tid >> 6, lane = tid & 63;
  int wm = wave & 1, wn = wave >> 1;
  int m0 = blockIdx.x * 128, n0 = blockIdx.y * 128;
  int lm = lane & 15, lq = lane >> 4;

  int c0_ = wave * 2;
  int r_in = lane >> 2;                     // 0..15
  int ps   = lane & 3;                      // physical 16B slot in 64B row
  int rowA0 = c0_ * 16 + r_in;              // chunk 2w row
  int rowA1 = rowA0 + 16;                   // chunk 2w+1 row
  int ls0 = ps ^ (rowA0 & 3);               // logical slot (inverse swizzle)
  int ls1 = ps ^ (rowA1 & 3);

  const bf16* gA0 = A  + (size_t)(m0 + rowA0) * Kdim + ls0 * 8;
  const bf16* gA1 = A  + (size_t)(m0 + rowA1) * Kdim + ls1 * 8;
  const bf16* gB0 = Bt + (size_t)(n0 + rowA0) * Kdim + ls0 * 8;
  const bf16* gB1 = Bt + (size_t)(n0 + rowA1) * Kdim + ls1 * 8;

  f32x4 zero = {0.f, 0.f, 0.f, 0.f};
  f32x4 acc[4][4];
  #pragma unroll
  for (int i = 0; i < 4; ++i)
    #pragma unroll
    for (int j = 0; j < 4; ++j) acc[i][j] = zero;

  int NK = Kdim >> 5;   // 24 for both gemms

  // prologue: stage tile0 -> buf0, tile1 -> buf1 (issue order matters for vmcnt)
  GLD16(gA0,      &smem[c0_ * 512]);
  GLD16(gA1,      &smem[c0_ * 512 + 512]);
  GLD16(gB0,      &smem[4096 + c0_ * 512]);
  GLD16(gB1,      &smem[4096 + c0_ * 512 + 512]);
  GLD16(gA0 + 32, &smem[8192 + c0_ * 512]);
  GLD16(gA1 + 32, &smem[8192 + c0_ * 512 + 512]);
  GLD16(gB0 + 32, &smem[8192 + 4096 + c0_ * 512]);
  GLD16(gB1 + 32, &smem[8192 + 4096 + c0_ * 512 + 512]);
  asm volatile("s_waitcnt vmcnt(4)" ::: "memory");   // tile0 landed; tile1 in flight
  LDS_BARRIER();

  int cur = 0;   // elems offset of current buf (rotates 0 -> 8192 -> 16384)
  for (int kk = 0; kk < NK; ++kk) {
    if (kk + 2 < NK) {           // issue tile kk+2 into buf[(kk+2)%3]
      int pre = cur + 16384; if (pre >= 24576) pre -= 24576;
      int k0 = (kk + 2) * 32;
      GLD16(gA0 + k0, &smem[pre + c0_ * 512]);
      GLD16(gA1 + k0, &smem[pre + c0_ * 512 + 512]);
      GLD16(gB0 + k0, &smem[pre + 4096 + c0_ * 512]);
      GLD16(gB1 + k0, &smem[pre + 4096 + c0_ * 512 + 512]);
    }

    bf16x8 af[4], bfr[4];
    #pragma unroll
    for (int i = 0; i < 4; ++i) {
      int ra = wm * 64 + i * 16 + lm;
      af[i] = *(const bf16x8*)(&smem[cur + ra * 32 + ((lq ^ (ra & 3)) * 8)]);
    }
    #pragma unroll
    for (int j = 0; j < 4; ++j) {
      int rb = wn * 64 + j * 16 + lm;
      bfr[j] = *(const bf16x8*)(&smem[cur + 4096 + rb * 32 + ((lq ^ (rb & 3)) * 8)]);
    }
    __builtin_amdgcn_s_setprio(1);
    #pragma unroll
    for (int i = 0; i < 4; ++i)
      #pragma unroll
      for (int j = 0; j < 4; ++j)
        acc[i][j] = __builtin_amdgcn_mfma_f32_16x16x32_bf16(af[i], bfr[j], acc[i][j], 0, 0, 0);
    __builtin_amdgcn_s_setprio(0);

    // retire tile kk+1 (next iter's data); tile kk+2's 4 loads stay in flight
    if (kk + 2 < NK) { asm volatile("s_waitcnt vmcnt(4)" ::: "memory"); }
    else             { asm volatile("s_waitcnt vmcnt(0)" ::: "memory"); }
    LDS_BARRIER();

    cur += 8192; if (cur >= 24576) cur = 0;
  }

  int mbase = m0 + wm * 64, nbase = n0 + wn * 64;
  #pragma unroll
  for (int j = 0; j < 4; ++j) {
    int n = nbase + j * 16 + lm;
    float bv_ = bias[n];
    if (MODE == 0) {
      #pragma unroll
      for (int i = 0; i < 4; ++i)
        #pragma unroll
        for (int r = 0; r < 4; ++r) {
          int m = mbase + i * 16 + lq * 4 + r;
          C[(size_t)m * Ndim + n] = acc[i][j][r] + bv_;
        }
    } else {
      int which = n / 768;             // uniform per block (768 = 6*128)
      int rem = n - which * 768;
      int h = rem >> 6, e = rem & 63;
      float scl = (which == 0) ? QSCALE2 : 1.0f;
      if (which == 2) {
        #pragma unroll
        for (int i = 0; i < 4; ++i)
          #pragma unroll
          for (int r = 0; r < 4; ++r) {
            int m = mbase + i * 16 + lq * 4 + r;
            int b = m >> 11, s = m & 2047;
            Vo[((size_t)(b * H_ + h) * 64 + e) * S_ + s] = (bf16)(acc[i][j][r] + bv_);
          }
      } else {
        bf16* dst = (which == 0) ? Qo : Ko;
        #pragma unroll
        for (int i = 0; i < 4; ++i)
          #pragma unroll
          for (int r = 0; r < 4; ++r) {
            int m = mbase + i * 16 + lq * 4 + r;
            int b = m >> 11, s = m & 2047;
            dst[((size_t)(b * H_ + h) * S_ + s) * 64 + e] = (bf16)((acc[i][j][r] + bv_) * scl);
          }
      }
    }
  }
}

// ---------------------------------------------------------------------------
// Flash attention v2 (r8 winner, UNTOUCHED): global_load_lds K/V staging,
// ping-pong LDS, issue-early/drain-late, 1 barrier/iter, rule-#21 swizzle,
// setprio around MFMA clusters. ~151 us measured steady-state.
// ---------------------------------------------------------------------------
__global__ __launch_bounds__(256, 4) void flash_attn(
    const bf16* __restrict__ Q, const bf16* __restrict__ K,
    const bf16* __restrict__ Vt, bf16* __restrict__ ctx)
{
  // elements: buf b at b*8192: [K 64x64 | V 64x64] (row stride 64 = 128 B)
  __shared__ bf16 smem[16384];   // 32768 B
  int tid = threadIdx.x;
  int wave = tid >> 6, lane = tid & 63;
  int lm = lane & 15, lq = lane >> 4;
  int x7 = lane & 7;

  int id = blockIdx.x;
  int xcd = id & 7, jj = id >> 3;
  int bh = xcd * 12 + (jj >> 4);
  int q0 = (jj & 15) * 128;

  const bf16* Qb = Q + (size_t)bh * S_ * 64;
  const bf16* Kb = K + (size_t)bh * S_ * 64;
  const bf16* Vb = Vt + (size_t)bh * 64 * S_;

  // staging geometry: chunk = 8 rows x 128 B = 1 KB; lane covers row rr=lane>>3,
  // physical slot lane&7; global fetch slot ls = (lane&7)^rr (inverse swizzle).
  int rr = lane >> 3;
  int ls = (lane & 7) ^ rr;
  const bf16* gk0 = Kb + (size_t)(wave * 16 + rr) * 64 + ls * 8;
  const bf16* gv0 = Vb + (size_t)(wave * 16 + rr) * S_ + ls * 8;

  // ---- prologue: stage Q -> buf1 region, tile0 K/V -> buf0, one full drain.
  {
    const bf16* gq = Qb + (size_t)(q0 + wave * 32 + rr) * 64 + ls * 8;
    #pragma unroll
    for (int c = 0; c < 4; ++c)
      GLD16(gq + (size_t)c * 512, &smem[8192 + (wave * 4 + c) * 512]);
    GLD16(gk0,                    &smem[wave * 1024]);
    GLD16(gk0 + 512,              &smem[wave * 1024 + 512]);
    GLD16(gv0,                    &smem[4096 + wave * 1024]);
    GLD16(gv0 + (size_t)8 * S_,   &smem[4096 + wave * 1024 + 512]);
  }
  __syncthreads();   // vmcnt(0)+lgkm(0)+barrier: Q and tile0 resident

  // hoist qf: Q[q0+qw+mi*16+lm][ks*32+lq*8..+7] via XOR'd slot
  int qw = wave * 32;
  bf16x8 qf[2][2];
  #pragma unroll
  for (int ks = 0; ks < 2; ++ks)
    #pragma unroll
    for (int mi = 0; mi < 2; ++mi)
      qf[ks][mi] = *(const bf16x8*)(&smem[8192 + (qw + mi * 16 + lm) * 64
                                          + ((ks * 4 + lq) ^ x7) * 8]);
  LDS_BARRIER();     // all hoist reads done before tile-1 staging hits buf1

  f32x4 zero = {0.f, 0.f, 0.f, 0.f};
  f32x4 O[2][4];           // O[q = qw+mi*16+lq*4+r][d = dj*16+lm]
  float lsum[2] = {0.f, 0.f};
  #pragma unroll
  for (int i = 0; i < 2; ++i)
    #pragma unroll
    for (int d = 0; d < 4; ++d) O[i][d] = zero;

  for (int t = 0; t < 32; ++t) {
    int cb = (t & 1) << 13;          // current buf base (elems)
    int nb = 8192 - cb;              // next buf base

    // issue tile t+1 staging EARLY (buf[nb]'s readers finished at barrier t-1)
    if (t + 1 < 32) {
      const bf16* gk = gk0 + (size_t)(t + 1) * 4096;   // +64 rows
      const bf16* gv = gv0 + (size_t)(t + 1) * 64;     // +64 cols
      GLD16(gk,                   &smem[nb + wave * 1024]);
      GLD16(gk + 512,             &smem[nb + wave * 1024 + 512]);
      GLD16(gv,                   &smem[nb + 4096 + wave * 1024]);
      GLD16(gv + (size_t)8 * S_,  &smem[nb + 4096 + wave * 1024 + 512]);
    }

    // ---- S^T = K Q^T : sacc[mi][ni] holds S^T[kv=ni*16+lq*4+r][q=qw+mi*16+lm]
    f32x4 sacc[2][4];
    #pragma unroll
    for (int i = 0; i < 2; ++i)
      #pragma unroll
      for (int j = 0; j < 4; ++j) sacc[i][j] = zero;
    __builtin_amdgcn_s_setprio(1);
    #pragma unroll
    for (int ks = 0; ks < 2; ++ks) {
      #pragma unroll
      for (int ni = 0; ni < 4; ++ni) {
        bf16x8 ak = *(const bf16x8*)(&smem[cb + (ni * 16 + lm) * 64
                                           + ((ks * 4 + lq) ^ x7) * 8]);
        sacc[0][ni] = __builtin_amdgcn_mfma_f32_16x16x32_bf16(ak, qf[ks][0], sacc[0][ni], 0, 0, 0);
        sacc[1][ni] = __builtin_amdgcn_mfma_f32_16x16x32_bf16(ak, qf[ks][1], sacc[1][ni], 0, 0, 0);
      }
    }
    __builtin_amdgcn_s_setprio(0);

    // ---- P = exp2(S'): S' already includes log2e via the Q pre-scale
    bf16x4 pexp[2][4];
    #pragma unroll
    for (int mi = 0; mi < 2; ++mi) {
      #pragma unroll
      for (int ni = 0; ni < 4; ++ni) {
        float e0 = EXP2(sacc[mi][ni][0]);
        float e1 = EXP2(sacc[mi][ni][1]);
        float e2 = EXP2(sacc[mi][ni][2]);
        float e3 = EXP2(sacc[mi][ni][3]);
        lsum[mi] += (e0 + e1) + (e2 + e3);
        bf16x4 px = {(bf16)e0, (bf16)e1, (bf16)e2, (bf16)e3};
        pexp[mi][ni] = px;
      }
    }

    // ---- O += P V : A = pexp (regs), B = V^T rows (b64 reads, XOR'd slot)
    __builtin_amdgcn_s_setprio(1);
    #pragma unroll
    for (int ni = 0; ni < 4; ++ni) {
      #pragma unroll
      for (int dj = 0; dj < 4; ++dj) {
        bf16x4 vb = *(const bf16x4*)(&smem[cb + 4096 + (dj * 16 + lm) * 64
                                           + ((ni * 2 + (lq >> 1)) ^ x7) * 8
                                           + (lq & 1) * 4]);
        O[0][dj] = mfma16(pexp[0][ni], vb, O[0][dj]);
        O[1][dj] = mfma16(pexp[1][ni], vb, O[1][dj]);
      }
    }
    __builtin_amdgcn_s_setprio(0);

    // my staging loads landed (latency hidden by the compute above), then
    // LDS-ordered barrier: next iter may read buf[nb] / overwrite buf[cb].
    asm volatile("s_waitcnt vmcnt(0)" ::: "memory");
    LDS_BARRIER();
  }

  // ---- final row-sum reduction: combine the 4 kv-quad groups (lq dim)
  float ls_[2];
  #pragma unroll
  for (int mi = 0; mi < 2; ++mi) {
    float rs = lsum[mi];
    rs += __shfl_xor(rs, 16);
    rs += __shfl_xor(rs, 32);
    ls_[mi] = rs;   // valid for q = qw + mi*16 + lm, all lanes with this lm
  }

  // ---- epilogue: ctx[b][s][h*64+d] = O / l
  int b = bh / H_, h = bh % H_;
  #pragma unroll
  for (int mi = 0; mi < 2; ++mi) {
    #pragma unroll
    for (int r = 0; r < 4; ++r) {
      int s = q0 + qw + mi * 16 + lq * 4 + r;
      float lv = __shfl(ls_[mi], lq * 4 + r);   // held by lane lm' = lq*4+r
      float linv = 1.0f / lv;
      #pragma unroll
      for (int dj = 0; dj < 4; ++dj) {
        int d = dj * 16 + lm;
        ctx[(size_t)(b * S_ + s) * D_ + h * 64 + d] = (bf16)(O[mi][dj][r] * linv);
      }
    }
  }
}

// ---------------------------------------------------------------------------
// Workspace layout (total 104,211,456 B = 99.38 MiB — must stay < 100 MiB):
//   [0      , 1*SZb)  xb   (bf16 x)    — reused as ctx after QKV gemm
//   [1*SZb  , 2*SZb)  Qb
//   [2*SZb  , 3*SZb)  Kb
//   [3*SZb  , 4*SZb)  Vtb
//   [4*SZb  , +3.54M) Wt [2304][768]   — dead after gemm_bt<1>; Wpt aliases it
//   [.. +9216)        ball (2304 f32)
// Wpt's transpose is launched AFTER gemm_bt<1> (stream-ordered), so aliasing
// Wpt onto Wt is safe and keeps the footprint under the workspace size.
// ---------------------------------------------------------------------------
extern "C" void kernel_launch(void* const* d_in, const int* in_sizes, int n_in,
                              void* d_out, int out_size, void* d_ws, size_t ws_size,
                              hipStream_t stream)
{
  const float* x  = (const float*)d_in[0];
  const float* Wq = (const float*)d_in[1];
  const float* bq = (const float*)d_in[2];
  const float* Wk = (const float*)d_in[3];
  const float* bk = (const float*)d_in[4];
  const float* Wv = (const float*)d_in[5];
  const float* bv = (const float*)d_in[6];
  const float* Wp = (const float*)d_in[7];
  const float* bp = (const float*)d_in[8];
  float* out = (float*)d_out;

  char* w = (char*)d_ws;
  const size_t SZ  = (size_t)BH_ * S_ * 64;   // 12,582,912 elems
  const size_t SZb = SZ * sizeof(bf16);       // 25,165,824 bytes
  bf16*  xb   = (bf16*)(w);                   // also reused as ctx
  bf16*  Qb   = (bf16*)(w + 1 * SZb);
  bf16*  Kb   = (bf16*)(w + 2 * SZb);
  bf16*  Vtb  = (bf16*)(w + 3 * SZb);
  bf16*  Wt   = (bf16*)(w + 4 * SZb);                       // [2304][768] bf16
  bf16*  Wpt  = Wt;   // aliases Wt: written after gemm_bt<1>, when Wt is dead
  float* ball = (float*)(w + 4 * SZb + 2304 * 768 * 2);
  bf16*  ctx  = xb;  // xb's last reader (QKV gemm) precedes flash_attn on stream

  // prep: x->bf16, fused {Wq|Wk|Wv transpose + bias pack}
  f2b<<<(int)(SZ / (256 * 8)), 256, 0, stream>>>(x, xb, (int)SZ);
  prep_w<<<dim3(12, 1, 37), 256, 0, stream>>>(Wq, Wk, Wv, bq, bk, bv, Wt, ball);

  // QKV projection -> Q(scaled)/K [B,H,S,64], V -> V^T [bh][64][S] (+bias)
  gemm_bt<1><<<dim3(128, 18), 256, 0, stream>>>(xb, Wt, ball, (float*)nullptr,
                                                Qb, Kb, Vtb, M_, 2304, 768);
  // Wp transpose AFTER Wt's last reader — Wpt aliases Wt's storage
  transpose64_f2b<<<dim3(12, 12, 1), 256, 0, stream>>>(Wp, Wpt, 768, 768);
  // attention (1536 blocks, XCD-swizzled decode inside)
  flash_attn<<<1536, 256, 0, stream>>>(Qb, Kb, Vtb, ctx);
  // output projection -> fp32 out
  gemm_bt<0><<<dim3(128, 6), 256, 0, stream>>>(ctx, Wpt, bp, out,
                                               (bf16*)nullptr, (bf16*)nullptr, (bf16*)nullptr,
                                               M_, 768, 768);
}

// Round 13
// 346.319 us; speedup vs baseline: 1.1058x; 1.0272x over previous
//
#include <hip/hip_runtime.h>
#include <hip/hip_bf16.h>
#include <stdint.h>

// Problem constants
#define B_  8
#define S_  2048
#define D_  768
#define H_  12
#define HD_ 64
#define BH_ (B_*H_)   // 96
#define M_  (B_*S_)   // 16384

typedef __bf16 bf16;
typedef __bf16 bf16x8 __attribute__((ext_vector_type(8)));
typedef __bf16 bf16x4 __attribute__((ext_vector_type(4)));
typedef short  short4v __attribute__((ext_vector_type(4)));
typedef float  f32x4  __attribute__((ext_vector_type(4)));

// Q pre-scale folds log2(e) so softmax uses native exp2 (v_exp_f32 IS exp2):
// 1/(8+1e-6) * log2(e); exp2(S*log2e) == exp(S).
#define QSCALE2 0.18033685756901243f

#if __has_builtin(__builtin_amdgcn_exp2f)
#define EXP2(x) __builtin_amdgcn_exp2f(x)
#else
#define EXP2(x) exp2f(x)
#endif

// LDS-only barrier: orders ds ops across the workgroup WITHOUT draining vmcnt.
#define LDS_BARRIER() asm volatile("s_waitcnt lgkmcnt(0)\n\ts_barrier" ::: "memory")

// global -> LDS direct copy, 16 B per lane (dest = uniform base + lane*16).
#define GLD16(gptr, lptr) __builtin_amdgcn_global_load_lds( \
    (const __attribute__((address_space(1))) uint32_t*)(gptr), \
    (__attribute__((address_space(3))) uint32_t*)(lptr), 16, 0, 0)

// 16x16x16 bf16 MFMA: A-layout == C/D-layout-transposed, the key identity.
#if __has_builtin(__builtin_amdgcn_mfma_f32_16x16x16bf16_1k)
static __device__ inline f32x4 mfma16(bf16x4 a, bf16x4 b, f32x4 c) {
  return __builtin_amdgcn_mfma_f32_16x16x16bf16_1k(
      __builtin_bit_cast(short4v, a), __builtin_bit_cast(short4v, b), c, 0, 0, 0);
}
#else
// fallback: zero-pad halves into the known-good 16x16x32 (same result)
static __device__ inline f32x4 mfma16(bf16x4 a, bf16x4 b, f32x4 c) {
  bf16 z = (bf16)0.f;
  bf16x8 a8 = {a[0], a[1], a[2], a[3], z, z, z, z};
  bf16x8 b8 = {b[0], b[1], b[2], b[3], z, z, z, z};
  return __builtin_amdgcn_mfma_f32_16x16x32_bf16(a8, b8, c, 0, 0, 0);
}
#endif

// ---------------------------------------------------------------------------
// fp32 -> bf16 elementwise convert, 8 elems/thread
// ---------------------------------------------------------------------------
__global__ __launch_bounds__(256) void f2b(const float* __restrict__ src,
                                           bf16* __restrict__ dst, int n) {
  int i = (blockIdx.x * 256 + threadIdx.x) * 8;
  if (i >= n) return;
  float4 a = *(const float4*)(src + i);
  float4 b = *(const float4*)(src + i + 4);
  bf16 o[8] = {(bf16)a.x, (bf16)a.y, (bf16)a.z, (bf16)a.w,
               (bf16)b.x, (bf16)b.y, (bf16)b.z, (bf16)b.w};
  *(uint4*)(dst + i) = *(const uint4*)o;
}

// ---------------------------------------------------------------------------
// 64x64-tile transpose + fp32->bf16: src f32 [mat][R][C] -> dst bf16 [mat][C][R]
// (still used for Wp)
// ---------------------------------------------------------------------------
__global__ __launch_bounds__(256) void transpose64_f2b(const float* __restrict__ src,
                                                       bf16* __restrict__ dst,
                                                       int R, int C) {
  __shared__ bf16 t[64][72];
  int mat = blockIdx.z;
  const float* s = src + (size_t)mat * R * C;
  bf16* d = dst + (size_t)mat * C * R;
  int r0 = blockIdx.x * 64, c0 = blockIdx.y * 64;
  int tid = threadIdx.x;
  #pragma unroll
  for (int it = 0; it < 4; ++it) {
    int i = (tid >> 4) + it * 16;
    int j = (tid & 15) * 4;
    float4 v = *(const float4*)(s + (size_t)(r0 + i) * C + c0 + j);
    t[j + 0][i] = (bf16)v.x; t[j + 1][i] = (bf16)v.y;
    t[j + 2][i] = (bf16)v.z; t[j + 3][i] = (bf16)v.w;
  }
  __syncthreads();
  #pragma unroll
  for (int it = 0; it < 4; ++it) {
    int i = (tid >> 4) + it * 16;
    int j = (tid & 15) * 4;
    bf16* p = d + (size_t)(c0 + i) * R + r0 + j;
    p[0] = t[i][j]; p[1] = t[i][j + 1]; p[2] = t[i][j + 2]; p[3] = t[i][j + 3];
  }
}

// ---------------------------------------------------------------------------
// Fused prep: transpose Wq|Wk|Wv (36 head-tiles of [768][64] -> [64][768])
// into Wt[2304][768], plus bias packing (z==36). Replaces 4 launches with 1.
// ---------------------------------------------------------------------------
__global__ __launch_bounds__(256) void prep_w(
    const float* __restrict__ Wq, const float* __restrict__ Wk,
    const float* __restrict__ Wv, const float* __restrict__ bq,
    const float* __restrict__ bk, const float* __restrict__ bv,
    bf16* __restrict__ Wt, float* __restrict__ ball)
{
  int z = blockIdx.z;
  int tid = threadIdx.x;
  if (z == 36) {   // bias pack: 12 blocks x 256 threads >= 2304
    int i = blockIdx.x * 256 + tid;
    if (i < 2304) {
      float v = (i < 768) ? bq[i] : (i < 1536 ? bk[i - 768] : bv[i - 1536]);
      ball[i] = v;
    }
    return;
  }
  __shared__ bf16 t[64][72];
  int w = z / 12, h = z % 12;
  const float* s = (w == 0 ? Wq : (w == 1 ? Wk : Wv)) + (size_t)h * 768 * 64;
  bf16* d = Wt + (size_t)z * 64 * 768;          // [64][768] head-tile
  int r0 = blockIdx.x * 64;                      // over R=768
  #pragma unroll
  for (int it = 0; it < 4; ++it) {
    int i = (tid >> 4) + it * 16;
    int j = (tid & 15) * 4;
    float4 v = *(const float4*)(s + (size_t)(r0 + i) * 64 + j);
    t[j + 0][i] = (bf16)v.x; t[j + 1][i] = (bf16)v.y;
    t[j + 2][i] = (bf16)v.z; t[j + 3][i] = (bf16)v.w;
  }
  __syncthreads();
  #pragma unroll
  for (int it = 0; it < 4; ++it) {
    int i = (tid >> 4) + it * 16;
    int j = (tid & 15) * 4;
    bf16* p = d + (size_t)i * 768 + r0 + j;
    p[0] = t[i][j]; p[1] = t[i][j + 1]; p[2] = t[i][j + 2]; p[3] = t[i][j + 3];
  }
}

// ---------------------------------------------------------------------------
// GEMM: C[M,N] = A[M,K](bf16) * Bt[N,K]^T(bf16) + bias[N](fp32)
// 128x128 tile, BK=32, 256 threads (4 waves, 2x2), mfma_f32_16x16x32_bf16.
// DISTANCE-2 async pipeline (r12, kept): 3 LDS buffers rotate; iter kk issues
// tile kk+2, computes kk, waits vmcnt(4) (retires kk+1, kk+2 in flight).
// __launch_bounds__(256,3), rule-#21 swizzle.
// MODE 0: fp32 row-major C. MODE 1: scatter Q (pre-scaled)/K to [B,H,S,64]
//         and V to V^T layout [bh][64][S] (bf16), all with bias.
// ---------------------------------------------------------------------------
template <int MODE>
__global__ __launch_bounds__(256, 3) void gemm_bt(
    const bf16* __restrict__ A, const bf16* __restrict__ Bt,
    const float* __restrict__ bias, float* __restrict__ C,
    bf16* __restrict__ Qo, bf16* __restrict__ Ko, bf16* __restrict__ Vo,
    int Mdim, int Ndim, int Kdim)
{
  // buf b at b*8192 elems: [As 4096 | Bs 4096]; 3 bufs, 48 KB total
  __shared__ bf16 smem[24576];
  int tid = threadIdx.x;
  int wave = tid >> 6, lane = tid & 63;
  int wm = wave & 1, wn = wave >> 1;
  int m0 = blockIdx.x * 128, n0 = blockIdx.y * 128;
  int lm = lane & 15, lq = lane >> 4;

  int c0_ = wave * 2;
  int r_in = lane >> 2;                     // 0..15
  int ps   = lane & 3;                      // physical 16B slot in 64B row
  int rowA0 = c0_ * 16 + r_in;              // chunk 2w row
  int rowA1 = rowA0 + 16;                   // chunk 2w+1 row
  int ls0 = ps ^ (rowA0 & 3);               // logical slot (inverse swizzle)
  int ls1 = ps ^ (rowA1 & 3);

  const bf16* gA0 = A  + (size_t)(m0 + rowA0) * Kdim + ls0 * 8;
  const bf16* gA1 = A  + (size_t)(m0 + rowA1) * Kdim + ls1 * 8;
  const bf16* gB0 = Bt + (size_t)(n0 + rowA0) * Kdim + ls0 * 8;
  const bf16* gB1 = Bt + (size_t)(n0 + rowA1) * Kdim + ls1 * 8;

  f32x4 zero = {0.f, 0.f, 0.f, 0.f};
  f32x4 acc[4][4];
  #pragma unroll
  for (int i = 0; i < 4; ++i)
    #pragma unroll
    for (int j = 0; j < 4; ++j) acc[i][j] = zero;

  int NK = Kdim >> 5;   // 24 for both gemms

  // prologue: stage tile0 -> buf0, tile1 -> buf1 (issue order matters for vmcnt)
  GLD16(gA0,      &smem[c0_ * 512]);
  GLD16(gA1,      &smem[c0_ * 512 + 512]);
  GLD16(gB0,      &smem[4096 + c0_ * 512]);
  GLD16(gB1,      &smem[4096 + c0_ * 512 + 512]);
  GLD16(gA0 + 32, &smem[8192 + c0_ * 512]);
  GLD16(gA1 + 32, &smem[8192 + c0_ * 512 + 512]);
  GLD16(gB0 + 32, &smem[8192 + 4096 + c0_ * 512]);
  GLD16(gB1 + 32, &smem[8192 + 4096 + c0_ * 512 + 512]);
  asm volatile("s_waitcnt vmcnt(4)" ::: "memory");   // tile0 landed; tile1 in flight
  LDS_BARRIER();

  int cur = 0;   // elems offset of current buf (rotates 0 -> 8192 -> 16384)
  for (int kk = 0; kk < NK; ++kk) {
    if (kk + 2 < NK) {           // issue tile kk+2 into buf[(kk+2)%3]
      int pre = cur + 16384; if (pre >= 24576) pre -= 24576;
      int k0 = (kk + 2) * 32;
      GLD16(gA0 + k0, &smem[pre + c0_ * 512]);
      GLD16(gA1 + k0, &smem[pre + c0_ * 512 + 512]);
      GLD16(gB0 + k0, &smem[pre + 4096 + c0_ * 512]);
      GLD16(gB1 + k0, &smem[pre + 4096 + c0_ * 512 + 512]);
    }

    bf16x8 af[4], bfr[4];
    #pragma unroll
    for (int i = 0; i < 4; ++i) {
      int ra = wm * 64 + i * 16 + lm;
      af[i] = *(const bf16x8*)(&smem[cur + ra * 32 + ((lq ^ (ra & 3)) * 8)]);
    }
    #pragma unroll
    for (int j = 0; j < 4; ++j) {
      int rb = wn * 64 + j * 16 + lm;
      bfr[j] = *(const bf16x8*)(&smem[cur + 4096 + rb * 32 + ((lq ^ (rb & 3)) * 8)]);
    }
    __builtin_amdgcn_s_setprio(1);
    #pragma unroll
    for (int i = 0; i < 4; ++i)
      #pragma unroll
      for (int j = 0; j < 4; ++j)
        acc[i][j] = __builtin_amdgcn_mfma_f32_16x16x32_bf16(af[i], bfr[j], acc[i][j], 0, 0, 0);
    __builtin_amdgcn_s_setprio(0);

    // retire tile kk+1 (next iter's data); tile kk+2's 4 loads stay in flight
    if (kk + 2 < NK) { asm volatile("s_waitcnt vmcnt(4)" ::: "memory"); }
    else             { asm volatile("s_waitcnt vmcnt(0)" ::: "memory"); }
    LDS_BARRIER();

    cur += 8192; if (cur >= 24576) cur = 0;
  }

  int mbase = m0 + wm * 64, nbase = n0 + wn * 64;
  #pragma unroll
  for (int j = 0; j < 4; ++j) {
    int n = nbase + j * 16 + lm;
    float bv_ = bias[n];
    if (MODE == 0) {
      #pragma unroll
      for (int i = 0; i < 4; ++i)
        #pragma unroll
        for (int r = 0; r < 4; ++r) {
          int m = mbase + i * 16 + lq * 4 + r;
          C[(size_t)m * Ndim + n] = acc[i][j][r] + bv_;
        }
    } else {
      int which = n / 768;             // uniform per block (768 = 6*128)
      int rem = n - which * 768;
      int h = rem >> 6, e = rem & 63;
      float scl = (which == 0) ? QSCALE2 : 1.0f;
      if (which == 2) {
        #pragma unroll
        for (int i = 0; i < 4; ++i)
          #pragma unroll
          for (int r = 0; r < 4; ++r) {
            int m = mbase + i * 16 + lq * 4 + r;
            int b = m >> 11, s = m & 2047;
            Vo[((size_t)(b * H_ + h) * 64 + e) * S_ + s] = (bf16)(acc[i][j][r] + bv_);
          }
      } else {
        bf16* dst = (which == 0) ? Qo : Ko;
        #pragma unroll
        for (int i = 0; i < 4; ++i)
          #pragma unroll
          for (int r = 0; r < 4; ++r) {
            int m = mbase + i * 16 + lq * 4 + r;
            int b = m >> 11, s = m & 2047;
            dst[((size_t)(b * H_ + h) * S_ + s) * 64 + e] = (bf16)((acc[i][j][r] + bv_) * scl);
          }
      }
    }
  }
}

// ---------------------------------------------------------------------------
// Flash attention v3: r8 pipeline + MFMA-based row-sum.
//  VALU was the top pipe (61% vs MFMA 44%). The 32 per-iter lsum adds are a
//  P-row-sum == P x ones matmul: 2 extra mfma16(pexp, ones, lacc) per ni
//  (8/iter) move them to the MFMA pipe. Bonus: ones-B result lands lacc[mi][r]
//  already in O's q-indexing (q = qw+mi*16+lq*4+r) -> the final shuffle
//  reduction disappears. exp fused into the per-ni PV loop so only pexp2[2]
//  is live (was pexp[2][4]): reg-neutral vs the 128 cap of (256,4).
//  l now sums bf16-rounded P (same values as the numerator) — ~1e-4 shift.
// ---------------------------------------------------------------------------
__global__ __launch_bounds__(256, 4) void flash_attn(
    const bf16* __restrict__ Q, const bf16* __restrict__ K,
    const bf16* __restrict__ Vt, bf16* __restrict__ ctx)
{
  // elements: buf b at b*8192: [K 64x64 | V 64x64] (row stride 64 = 128 B)
  __shared__ bf16 smem[16384];   // 32768 B
  int tid = threadIdx.x;
  int wave = tid >> 6, lane = tid & 63;
  int lm = lane & 15, lq = lane >> 4;
  int x7 = lane & 7;

  int id = blockIdx.x;
  int xcd = id & 7, jj = id >> 3;
  int bh = xcd * 12 + (jj >> 4);
  int q0 = (jj & 15) * 128;

  const bf16* Qb = Q + (size_t)bh * S_ * 64;
  const bf16* Kb = K + (size_t)bh * S_ * 64;
  const bf16* Vb = Vt + (size_t)bh * 64 * S_;

  // staging geometry: chunk = 8 rows x 128 B = 1 KB; lane covers row rr=lane>>3,
  // physical slot lane&7; global fetch slot ls = (lane&7)^rr (inverse swizzle).
  int rr = lane >> 3;
  int ls = (lane & 7) ^ rr;
  const bf16* gk0 = Kb + (size_t)(wave * 16 + rr) * 64 + ls * 8;
  const bf16* gv0 = Vb + (size_t)(wave * 16 + rr) * S_ + ls * 8;

  // ---- prologue: stage Q -> buf1 region, tile0 K/V -> buf0, one full drain.
  {
    const bf16* gq = Qb + (size_t)(q0 + wave * 32 + rr) * 64 + ls * 8;
    #pragma unroll
    for (int c = 0; c < 4; ++c)
      GLD16(gq + (size_t)c * 512, &smem[8192 + (wave * 4 + c) * 512]);
    GLD16(gk0,                    &smem[wave * 1024]);
    GLD16(gk0 + 512,              &smem[wave * 1024 + 512]);
    GLD16(gv0,                    &smem[4096 + wave * 1024]);
    GLD16(gv0 + (size_t)8 * S_,   &smem[4096 + wave * 1024 + 512]);
  }
  __syncthreads();   // vmcnt(0)+lgkm(0)+barrier: Q and tile0 resident

  // hoist qf: Q[q0+qw+mi*16+lm][ks*32+lq*8..+7] via XOR'd slot
  int qw = wave * 32;
  bf16x8 qf[2][2];
  #pragma unroll
  for (int ks = 0; ks < 2; ++ks)
    #pragma unroll
    for (int mi = 0; mi < 2; ++mi)
      qf[ks][mi] = *(const bf16x8*)(&smem[8192 + (qw + mi * 16 + lm) * 64
                                          + ((ks * 4 + lq) ^ x7) * 8]);
  LDS_BARRIER();     // all hoist reads done before tile-1 staging hits buf1

  f32x4 zero = {0.f, 0.f, 0.f, 0.f};
  f32x4 O[2][4];           // O[q = qw+mi*16+lq*4+r][d = dj*16+lm]
  f32x4 lacc[2];           // lacc[mi][r] = sum_kv P[kv][q], q = qw+mi*16+lq*4+r
  bf16 one_ = (bf16)1.f;
  bf16x4 ones = {one_, one_, one_, one_};
  #pragma unroll
  for (int i = 0; i < 2; ++i) {
    lacc[i] = zero;
    #pragma unroll
    for (int d = 0; d < 4; ++d) O[i][d] = zero;
  }

  for (int t = 0; t < 32; ++t) {
    int cb = (t & 1) << 13;          // current buf base (elems)
    int nb = 8192 - cb;              // next buf base

    // issue tile t+1 staging EARLY (buf[nb]'s readers finished at barrier t-1)
    if (t + 1 < 32) {
      const bf16* gk = gk0 + (size_t)(t + 1) * 4096;   // +64 rows
      const bf16* gv = gv0 + (size_t)(t + 1) * 64;     // +64 cols
      GLD16(gk,                   &smem[nb + wave * 1024]);
      GLD16(gk + 512,             &smem[nb + wave * 1024 + 512]);
      GLD16(gv,                   &smem[nb + 4096 + wave * 1024]);
      GLD16(gv + (size_t)8 * S_,  &smem[nb + 4096 + wave * 1024 + 512]);
    }

    // ---- S^T = K Q^T : sacc[mi][ni] holds S^T[kv=ni*16+lq*4+r][q=qw+mi*16+lm]
    f32x4 sacc[2][4];
    #pragma unroll
    for (int i = 0; i < 2; ++i)
      #pragma unroll
      for (int j = 0; j < 4; ++j) sacc[i][j] = zero;
    __builtin_amdgcn_s_setprio(1);
    #pragma unroll
    for (int ks = 0; ks < 2; ++ks) {
      #pragma unroll
      for (int ni = 0; ni < 4; ++ni) {
        bf16x8 ak = *(const bf16x8*)(&smem[cb + (ni * 16 + lm) * 64
                                           + ((ks * 4 + lq) ^ x7) * 8]);
        sacc[0][ni] = __builtin_amdgcn_mfma_f32_16x16x32_bf16(ak, qf[ks][0], sacc[0][ni], 0, 0, 0);
        sacc[1][ni] = __builtin_amdgcn_mfma_f32_16x16x32_bf16(ak, qf[ks][1], sacc[1][ni], 0, 0, 0);
      }
    }
    __builtin_amdgcn_s_setprio(0);

    // ---- fused P = exp2(S') and O += P V, per ni (pexp2 live set = 2 regs)
    #pragma unroll
    for (int ni = 0; ni < 4; ++ni) {
      bf16x4 pexp2[2];
      #pragma unroll
      for (int mi = 0; mi < 2; ++mi) {
        float e0 = EXP2(sacc[mi][ni][0]);
        float e1 = EXP2(sacc[mi][ni][1]);
        float e2 = EXP2(sacc[mi][ni][2]);
        float e3 = EXP2(sacc[mi][ni][3]);
        bf16x4 px = {(bf16)e0, (bf16)e1, (bf16)e2, (bf16)e3};
        pexp2[mi] = px;
      }
      __builtin_amdgcn_s_setprio(1);
      #pragma unroll
      for (int dj = 0; dj < 4; ++dj) {
        bf16x4 vb = *(const bf16x4*)(&smem[cb + 4096 + (dj * 16 + lm) * 64
                                           + ((ni * 2 + (lq >> 1)) ^ x7) * 8
                                           + (lq & 1) * 4]);
        O[0][dj] = mfma16(pexp2[0], vb, O[0][dj]);
        O[1][dj] = mfma16(pexp2[1], vb, O[1][dj]);
      }
      // row-sum via ones-B matmul: lacc[mi][r] += sum_kv(ni slice) P[kv][q]
      lacc[0] = mfma16(pexp2[0], ones, lacc[0]);
      lacc[1] = mfma16(pexp2[1], ones, lacc[1]);
      __builtin_amdgcn_s_setprio(0);
    }

    // my staging loads landed (latency hidden by the compute above), then
    // LDS-ordered barrier: next iter may read buf[nb] / overwrite buf[cb].
    asm volatile("s_waitcnt vmcnt(0)" ::: "memory");
    LDS_BARRIER();
  }

  // ---- epilogue: ctx[b][s][h*64+d] = O / l ; lacc already in O's q-indexing
  int b = bh / H_, h = bh % H_;
  #pragma unroll
  for (int mi = 0; mi < 2; ++mi) {
    #pragma unroll
    for (int r = 0; r < 4; ++r) {
      int s = q0 + qw + mi * 16 + lq * 4 + r;
      float linv = 1.0f / lacc[mi][r];
      #pragma unroll
      for (int dj = 0; dj < 4; ++dj) {
        int d = dj * 16 + lm;
        ctx[(size_t)(b * S_ + s) * D_ + h * 64 + d] = (bf16)(O[mi][dj][r] * linv);
      }
    }
  }
}

// ---------------------------------------------------------------------------
// Workspace layout (total 104,211,456 B = 99.38 MiB — must stay < 100 MiB):
//   [0      , 1*SZb)  xb   (bf16 x)    — reused as ctx after QKV gemm
//   [1*SZb  , 2*SZb)  Qb
//   [2*SZb  , 3*SZb)  Kb
//   [3*SZb  , 4*SZb)  Vtb
//   [4*SZb  , +3.54M) Wt [2304][768]   — dead after gemm_bt<1>; Wpt aliases it
//   [.. +9216)        ball (2304 f32)
// Wpt's transpose is launched AFTER gemm_bt<1> (stream-ordered), so aliasing
// Wpt onto Wt is safe and keeps the footprint under the workspace size.
// ---------------------------------------------------------------------------
extern "C" void kernel_launch(void* const* d_in, const int* in_sizes, int n_in,
                              void* d_out, int out_size, void* d_ws, size_t ws_size,
                              hipStream_t stream)
{
  const float* x  = (const float*)d_in[0];
  const float* Wq = (const float*)d_in[1];
  const float* bq = (const float*)d_in[2];
  const float* Wk = (const float*)d_in[3];
  const float* bk = (const float*)d_in[4];
  const float* Wv = (const float*)d_in[5];
  const float* bv = (const float*)d_in[6];
  const float* Wp = (const float*)d_in[7];
  const float* bp = (const float*)d_in[8];
  float* out = (float*)d_out;

  char* w = (char*)d_ws;
  const size_t SZ  = (size_t)BH_ * S_ * 64;   // 12,582,912 elems
  const size_t SZb = SZ * sizeof(bf16);       // 25,165,824 bytes
  bf16*  xb   = (bf16*)(w);                   // also reused as ctx
  bf16*  Qb   = (bf16*)(w + 1 * SZb);
  bf16*  Kb   = (bf16*)(w + 2 * SZb);
  bf16*  Vtb  = (bf16*)(w + 3 * SZb);
  bf16*  Wt   = (bf16*)(w + 4 * SZb);                       // [2304][768] bf16
  bf16*  Wpt  = Wt;   // aliases Wt: written after gemm_bt<1>, when Wt is dead
  float* ball = (float*)(w + 4 * SZb + 2304 * 768 * 2);
  bf16*  ctx  = xb;  // xb's last reader (QKV gemm) precedes flash_attn on stream

  // prep: x->bf16, fused {Wq|Wk|Wv transpose + bias pack}
  f2b<<<(int)(SZ / (256 * 8)), 256, 0, stream>>>(x, xb, (int)SZ);
  prep_w<<<dim3(12, 1, 37), 256, 0, stream>>>(Wq, Wk, Wv, bq, bk, bv, Wt, ball);

  // QKV projection -> Q(scaled)/K [B,H,S,64], V -> V^T [bh][64][S] (+bias)
  gemm_bt<1><<<dim3(128, 18), 256, 0, stream>>>(xb, Wt, ball, (float*)nullptr,
                                                Qb, Kb, Vtb, M_, 2304, 768);
  // Wp transpose AFTER Wt's last reader — Wpt aliases Wt's storage
  transpose64_f2b<<<dim3(12, 12, 1), 256, 0, stream>>>(Wp, Wpt, 768, 768);
  // attention (1536 blocks, XCD-swizzled decode inside)
  flash_attn<<<1536, 256, 0, stream>>>(Qb, Kb, Vtb, ctx);
  // output projection -> fp32 out
  gemm_bt<0><<<dim3(128, 6), 256, 0, stream>>>(ctx, Wpt, bp, out,
                                               (bf16*)nullptr, (bf16*)nullptr, (bf16*)nullptr,
                                               M_, 768, 768);
}